// Round 10
// baseline (3538.711 us; speedup 1.0000x reference)
//
#include <hip/hip_runtime.h>
#include <math.h>

#define BB 2
#define SS 1024
#define DD 1024
#define NN 64
#define LLAYERS 4
#define KCC 4
#define KLL 4
#define VV 32000
#define MM (BB*SS)          // 2048
#define M2 (2*MM)           // 4096
#define PS ((size_t)MM*DD)  // 2097152 floats per plane
#define CH 4                // time chunks for scan
#define LC (SS/CH)          // 256 steps per chunk
#define BDW (BB*DD)         // 2048 (b,d) pairs

#define SCALE_F 0.35355339059327373f
#define GAMMA_F 0.01f
#define PHASE_COS 0.99500416527802576f
#define PHASE_SIN 0.09983341664682815f

typedef _Float16 f16x8 __attribute__((ext_vector_type(8)));
typedef _Float16 f16x4 __attribute__((ext_vector_type(4)));
typedef float f32x4 __attribute__((ext_vector_type(4)));

__device__ __forceinline__ float softplus_f(float x) {
    return fmaxf(x, 0.f) + log1pf(expf(-fabsf(x)));
}

__device__ __forceinline__ void async16(void* lds_dst, const void* g_src) {
    __builtin_amdgcn_global_load_lds(
        (const __attribute__((address_space(1))) unsigned int*)g_src,
        (__attribute__((address_space(3))) unsigned int*)lds_dst,
        16, 0, 0);
}

// 16-lane row-sum (VALU DPP row_shr tree). Partial sum valid in lane 15 mod 16.
__device__ __forceinline__ float rsum16_dpp(float v) {
    int x;
    x = __float_as_int(v);
    v += __int_as_float(__builtin_amdgcn_update_dpp(0, x, 0x111, 0xf, 0xf, true));
    x = __float_as_int(v);
    v += __int_as_float(__builtin_amdgcn_update_dpp(0, x, 0x112, 0xf, 0xf, true));
    x = __float_as_int(v);
    v += __int_as_float(__builtin_amdgcn_update_dpp(0, x, 0x114, 0xf, 0xf, true));
    x = __float_as_int(v);
    v += __int_as_float(__builtin_amdgcn_update_dpp(0, x, 0x118, 0xf, 0xf, true));
    return v;
}

// ---------------- K0: transpose + f16 hi/lo split of weights ----------------
__global__ __launch_bounds__(256) void k_split_w(const float* __restrict__ W,
        _Float16* __restrict__ Wh, _Float16* __restrict__ Wl, int Ksz, int Nsz) {
    __shared__ float t[32][33];
    int k0 = blockIdx.x * 32, n0 = blockIdx.y * 32;
    size_t base = (size_t)blockIdx.z * Ksz * Nsz;
    int r = threadIdx.x >> 3, c4 = (threadIdx.x & 7) * 4;
    float4 v = *(const float4*)(W + base + (size_t)(k0 + r) * Nsz + n0 + c4);
    t[r][c4 + 0] = v.x; t[r][c4 + 1] = v.y; t[r][c4 + 2] = v.z; t[r][c4 + 3] = v.w;
    __syncthreads();
    f16x4 hi, lo;
    #pragma unroll
    for (int j = 0; j < 4; ++j) {
        float x = t[c4 + j][r];
        _Float16 h = (_Float16)x;
        hi[j] = h; lo[j] = (_Float16)(x - (float)h);
    }
    size_t o = base + (size_t)(n0 + r) * Ksz + k0 + c4;
    *(f16x4*)(Wh + o) = hi;
    *(f16x4*)(Wl + o) = lo;
}

// ---------------- K1: embedding gather + psi f16 split ----------------
__global__ __launch_bounds__(256) void k_embed(const int* __restrict__ tok,
        const float* __restrict__ er, const float* __restrict__ ei,
        float* __restrict__ Pr, float* __restrict__ Pi,
        _Float16* __restrict__ Ph, _Float16* __restrict__ Pl) {
    int i = blockIdx.x * 256 + threadIdx.x;      // over PS/4
    int d4 = (i & (DD/4 - 1)) * 4;
    int m  = i >> 8;
    int t = tok[m];
    float4 r  = *(const float4*)(er + (size_t)t * DD + d4);
    float4 im = *(const float4*)(ei + (size_t)t * DD + d4);
    size_t o = (size_t)m * DD + d4;
    *(float4*)(Pr + o) = r;
    *(float4*)(Pi + o) = im;
    float vr[4] = {r.x, r.y, r.z, r.w}, vi[4] = {im.x, im.y, im.z, im.w};
    f16x4 rh, rl, ih, il;
    #pragma unroll
    for (int j = 0; j < 4; ++j) {
        _Float16 h = (_Float16)vr[j]; rh[j] = h; rl[j] = (_Float16)(vr[j] - (float)h);
        _Float16 g = (_Float16)vi[j]; ih[j] = g; il[j] = (_Float16)(vi[j] - (float)g);
    }
    *(f16x4*)(Ph + o) = rh;      *(f16x4*)(Pl + o) = rl;
    *(f16x4*)(Ph + PS + o) = ih; *(f16x4*)(Pl + PS + o) = il;
}

// ---------------- K2: f16-split MFMA GEMM: C(M2 x N) = A @ B^T ----------------
__global__ __launch_bounds__(256, 2) void k_gemm_f16(
        const _Float16* __restrict__ Ah, const _Float16* __restrict__ Al,
        const _Float16* __restrict__ Bh, const _Float16* __restrict__ Bl,
        float* __restrict__ C, int Nsz) {
    __shared__ __align__(16) unsigned char lds[32768];
    const int lane = threadIdx.x & 63;
    const int wid  = threadIdx.x >> 6;
    const int wm = (wid >> 1) * 64;
    const int wv = (wid & 1) * 64;
    const int n0 = blockIdx.x * 128;
    const int m0 = blockIdx.y * 128;
    const int fr = lane & 15, fq = lane >> 4;

    f32x4 acc[4][4] = {};

    for (int k0 = 0; k0 < 1024; k0 += 32) {
        #pragma unroll
        for (int j = 0; j < 8; ++j) {
            int cid = wid * 8 + j;
            int sel = cid >> 3, c = cid & 7;
            const _Float16* bp = (sel == 0) ? Ah : (sel == 1) ? Al : (sel == 2) ? Bh : Bl;
            int rbase = ((sel < 2) ? m0 : n0) + c * 16 + fr;
            async16(lds + cid * 1024, bp + (size_t)rbase * 1024 + k0 + fq * 8);
        }
        __syncthreads();

        f16x8 ah[4], al[4];
        #pragma unroll
        for (int ms = 0; ms < 4; ++ms) {
            int off = ((wm >> 4) + ms) * 1024 + lane * 16;
            ah[ms] = *(const f16x8*)(lds + off);
            al[ms] = *(const f16x8*)(lds + 8192 + off);
        }
        #pragma unroll
        for (int vs = 0; vs < 4; ++vs) {
            int boff = ((wv >> 4) + vs) * 1024 + lane * 16;
            f16x8 bh = *(const f16x8*)(lds + 16384 + boff);
            f16x8 bl = *(const f16x8*)(lds + 24576 + boff);
            #pragma unroll
            for (int ms = 0; ms < 4; ++ms) {
                acc[ms][vs] = __builtin_amdgcn_mfma_f32_16x16x32_f16(ah[ms], bh, acc[ms][vs], 0, 0, 0);
                acc[ms][vs] = __builtin_amdgcn_mfma_f32_16x16x32_f16(ah[ms], bl, acc[ms][vs], 0, 0, 0);
                acc[ms][vs] = __builtin_amdgcn_mfma_f32_16x16x32_f16(al[ms], bh, acc[ms][vs], 0, 0, 0);
            }
        }
        __syncthreads();
    }

    #pragma unroll
    for (int ms = 0; ms < 4; ++ms) {
        #pragma unroll
        for (int vs = 0; vs < 4; ++vs) {
            #pragma unroll
            for (int r = 0; r < 4; ++r) {
                int row = m0 + wm + ms * 16 + fq * 4 + r;
                int col = n0 + wv + vs * 16 + fr;
                C[(size_t)row * Nsz + col] = acc[ms][vs][r];
            }
        }
    }
}

// ---------------- K2b: 128x64-tile f16-split GEMM (N=1024 path) ----------------
__global__ __launch_bounds__(256, 2) void k_gemm_n64(
        const _Float16* __restrict__ Ah, const _Float16* __restrict__ Al,
        const _Float16* __restrict__ Bh, const _Float16* __restrict__ Bl,
        float* __restrict__ C, int Nsz) {
    __shared__ __align__(16) unsigned char lds[24576];
    const int lane = threadIdx.x & 63;
    const int wid  = threadIdx.x >> 6;
    const int wm = (wid >> 1) * 64;
    const int wv = (wid & 1) * 32;
    const int n0 = blockIdx.x * 64;
    const int m0 = blockIdx.y * 128;
    const int fr = lane & 15, fq = lane >> 4;

    f32x4 acc[4][2] = {};

    for (int k0 = 0; k0 < 1024; k0 += 32) {
        #pragma unroll
        for (int j = 0; j < 6; ++j) {
            int cid = j * 4 + wid;
            const _Float16* bp;
            int rbase, ldsoff;
            if (cid < 16) {           // A: plane cid>>3, 16-row subtile cid&7
                bp = (cid >> 3) ? Al : Ah;
                rbase = m0 + (cid & 7) * 16 + fr;
                ldsoff = cid * 1024;
            } else {                  // B: plane (cid-16)>>2, subtile (cid-16)&3
                int r = cid - 16;
                bp = (r >> 2) ? Bl : Bh;
                rbase = n0 + (r & 3) * 16 + fr;
                ldsoff = 16384 + r * 1024;
            }
            async16(lds + ldsoff, bp + (size_t)rbase * 1024 + k0 + fq * 8);
        }
        __syncthreads();

        f16x8 ah[4], al[4];
        #pragma unroll
        for (int ms = 0; ms < 4; ++ms) {
            int off = ((wm >> 4) + ms) * 1024 + lane * 16;
            ah[ms] = *(const f16x8*)(lds + off);
            al[ms] = *(const f16x8*)(lds + 8192 + off);
        }
        #pragma unroll
        for (int vs = 0; vs < 2; ++vs) {
            int boff = ((wv >> 4) + vs) * 1024 + lane * 16;
            f16x8 bh = *(const f16x8*)(lds + 16384 + boff);
            f16x8 bl = *(const f16x8*)(lds + 20480 + boff);
            #pragma unroll
            for (int ms = 0; ms < 4; ++ms) {
                acc[ms][vs] = __builtin_amdgcn_mfma_f32_16x16x32_f16(ah[ms], bh, acc[ms][vs], 0, 0, 0);
                acc[ms][vs] = __builtin_amdgcn_mfma_f32_16x16x32_f16(ah[ms], bl, acc[ms][vs], 0, 0, 0);
                acc[ms][vs] = __builtin_amdgcn_mfma_f32_16x16x32_f16(al[ms], bh, acc[ms][vs], 0, 0, 0);
            }
        }
        __syncthreads();
    }

    #pragma unroll
    for (int ms = 0; ms < 4; ++ms) {
        #pragma unroll
        for (int vs = 0; vs < 2; ++vs) {
            #pragma unroll
            for (int r = 0; r < 4; ++r) {
                int row = m0 + wm + ms * 16 + fq * 4 + r;
                int col = n0 + wv + vs * 16 + fr;
                C[(size_t)row * Nsz + col] = acc[ms][vs][r];
            }
        }
    }
}

// ---------------- K3: causal depthwise conv + csilu + dt + z-gate (x4 vec) ----------------
__global__ __launch_bounds__(256) void k_conv(const float* __restrict__ XZ,
        const float* __restrict__ ck, const float* __restrict__ dts,
        const float* __restrict__ dtb,
        float* __restrict__ Xr, float* __restrict__ Xi, float* __restrict__ DT,
        float* __restrict__ ZUr, float* __restrict__ ZUi) {
    int i4 = blockIdx.x * 256 + threadIdx.x;     // over MM*DD/4
    int dq = (i4 & (DD / 4 - 1)) * 4;
    int m  = i4 >> 8;
    int b = m >> 10, s = m & (SS - 1);
    size_t i = (size_t)m * DD + dq;
    float kw[4][4];
    #pragma unroll
    for (int c = 0; c < 4; ++c)
        *(float4*)kw[c] = *(const float4*)(ck + (size_t)(dq + c) * KCC);
    float cr[4] = {0.f, 0.f, 0.f, 0.f}, ci[4] = {0.f, 0.f, 0.f, 0.f};
    #pragma unroll
    for (int j = 0; j < KCC; ++j) {
        int sj = s - (KCC - 1) + j;
        if (sj >= 0) {
            size_t mm = ((size_t)(b << 10) + sj) * 2048 + dq;
            float4 xr4 = *(const float4*)(XZ + mm);
            float4 xi4 = *(const float4*)(XZ + (size_t)MM * 2048 + mm);
            float xr_[4] = {xr4.x, xr4.y, xr4.z, xr4.w};
            float xi_[4] = {xi4.x, xi4.y, xi4.z, xi4.w};
            #pragma unroll
            for (int c = 0; c < 4; ++c) {
                cr[c] = fmaf(xr_[c], kw[c][j], cr[c]);
                ci[c] = fmaf(xi_[c], kw[c][j], ci[c]);
            }
        }
    }
    float4 dts4 = *(const float4*)(dts + dq);
    float4 dtb4 = *(const float4*)(dtb + dq);
    float dts_[4] = {dts4.x, dts4.y, dts4.z, dts4.w};
    float dtb_[4] = {dtb4.x, dtb4.y, dtb4.z, dtb4.w};
    float xro[4], xio[4], dto[4];
    #pragma unroll
    for (int c = 0; c < 4; ++c) {
        float mag = sqrtf(cr[c] * cr[c] + ci[c] * ci[c]);
        float sg = 1.f / (1.f + expf(-mag));
        xro[c] = cr[c] * sg; xio[c] = ci[c] * sg;
        dto[c] = softplus_f(fmaf(xro[c], dts_[c], dtb_[c]));
    }
    *(float4*)(Xr + i) = make_float4(xro[0], xro[1], xro[2], xro[3]);
    *(float4*)(Xi + i) = make_float4(xio[0], xio[1], xio[2], xio[3]);
    *(float4*)(DT + i) = make_float4(dto[0], dto[1], dto[2], dto[3]);
    float4 zr4 = *(const float4*)(XZ + (size_t)m * 2048 + DD + dq);
    float4 zi4 = *(const float4*)(XZ + (size_t)(MM + m) * 2048 + DD + dq);
    float zr_[4] = {zr4.x, zr4.y, zr4.z, zr4.w};
    float zi_[4] = {zi4.x, zi4.y, zi4.z, zi4.w};
    float zur[4], zui[4];
    #pragma unroll
    for (int c = 0; c < 4; ++c) {
        float mz = sqrtf(zr_[c] * zr_[c] + zi_[c] * zi_[c]);
        float sz = 1.f / (1.f + expf(-mz));
        zur[c] = zr_[c] * sz; zui[c] = zi_[c] * sz;
    }
    *(float4*)(ZUr + i) = make_float4(zur[0], zur[1], zur[2], zur[3]);
    *(float4*)(ZUi + i) = make_float4(zui[0], zui[1], zui[2], zui[3]);
}

// ---------------- K4: Bc/Cc projections -> packed BC2[(m*64+n)*4 + {br,bi,cr,ci}] ----------------
__global__ __launch_bounds__(256) void k_bc(const float* __restrict__ X,
        const float* __restrict__ WBp, const float* __restrict__ WCp,
        float* __restrict__ BC2) {
    __shared__ float xs[4][DD];
    __shared__ float red[4 * 256];
    int r0 = blockIdx.x * 4;
    for (int f = threadIdx.x; f < 4 * (DD / 4); f += 256) {
        int r = f / (DD / 4), c = (f % (DD / 4)) * 4;
        *(float4*)(&xs[r][c]) = *(const float4*)(X + (size_t)(r0 + r) * DD + c);
    }
    __syncthreads();
    int out = threadIdx.x & 127;
    int half = threadIdx.x >> 7;
    const float* Wrow = (out < 64) ? (WBp + (size_t)out * DD) : (WCp + (size_t)(out - 64) * DD);
    float acc[4] = {0.f, 0.f, 0.f, 0.f};
    for (int k = half * 512; k < half * 512 + 512; k += 4) {
        float4 w = *(const float4*)(Wrow + k);
        #pragma unroll
        for (int r = 0; r < 4; ++r) {
            float4 x4 = *(float4*)(&xs[r][k]);
            acc[r] = fmaf(x4.x, w.x, fmaf(x4.y, w.y, fmaf(x4.z, w.z, fmaf(x4.w, w.w, acc[r]))));
        }
    }
    #pragma unroll
    for (int r = 0; r < 4; ++r) red[r * 256 + threadIdx.x] = acc[r];
    __syncthreads();
    if (threadIdx.x < 128) {
        int isIm = (r0 >= MM) ? 1 : 0;
        int n = out & 63;
        int comp = ((out >> 6) << 1) | isIm;   // br=0, bi=1, cr=2, ci=3
        #pragma unroll
        for (int r = 0; r < 4; ++r) {
            float v = red[r * 256 + threadIdx.x] + red[r * 256 + threadIdx.x + 128];
            int m = (r0 + r) & (MM - 1);
            BC2[((size_t)m * 64 + n) * 4 + comp] = v;
        }
    }
}

// ---------------- K5a: scan pass 1, 4-step unrolled, 16-lane partial reduce ----------------
__global__ __launch_bounds__(256, 8) void k_scan1(const float* __restrict__ X,
        const float* __restrict__ DT, const float4* __restrict__ BC2,
        const float* __restrict__ Alog, float* __restrict__ Y8T,
        float2* __restrict__ HB, float* __restrict__ SDT) {
    int w = (blockIdx.x << 2) + (threadIdx.x >> 6);   // (bd, c)
    int lane = threadIdx.x & 63;
    int c = w & (CH - 1);
    int bd = w >> 2;
    int b = bd >> 10, d = bd & (DD - 1);
    float Av = -__expf(Alog[(size_t)d * NN + lane]);
    float hr = 0.f, hi = 0.f, sdt = 0.f;
    int s0 = c * LC;
    size_t mBase = (size_t)(b << 10);
    size_t md = (mBase + s0) * DD + d;
    const float4* bcp = BC2 + (mBase + s0) * 64 + lane;
    size_t ys = (size_t)bd * SS + s0;
    size_t po = (size_t)(lane >> 4) * 2 * PS;
    for (int t = 0; t < LC; t += 4) {
        float4 yrq, yiq;
        #pragma unroll
        for (int k = 0; k < 4; ++k) {
            float dt = DT[md], xr = X[md], xi = X[PS + md];
            float4 bc = bcp[(size_t)k * 64];
            float g = __expf(dt * Av);
            float dxr = dt * xr, dxi = dt * xi;
            hr = fmaf(g, hr, fmaf(dxr, bc.x, -dxi * bc.y));
            hi = fmaf(g, hi, fmaf(dxr, bc.y,  dxi * bc.x));
            sdt += dt;
            float pr = rsum16_dpp(hr * bc.z - hi * bc.w);
            float pi = rsum16_dpp(hr * bc.w + hi * bc.z);
            if (k == 0)      { yrq.x = pr; yiq.x = pi; }
            else if (k == 1) { yrq.y = pr; yiq.y = pi; }
            else if (k == 2) { yrq.z = pr; yiq.z = pi; }
            else             { yrq.w = pr; yiq.w = pi; }
            md += DD;
        }
        bcp += 256;
        if ((lane & 15) == 15) {
            *(float4*)(Y8T + po + ys)      = yrq;
            *(float4*)(Y8T + po + PS + ys) = yiq;
        }
        ys += 4;
    }
    HB[((size_t)c * BDW + bd) * NN + lane] = make_float2(hr, hi);
    if (lane == 0) SDT[c * BDW + bd] = sdt;
}

// ---------------- K5c: inflow correction, 4-step unrolled, partial RMW ----------------
__global__ __launch_bounds__(256, 8) void k_scan3(const float* __restrict__ DT,
        const float* __restrict__ BC2, const float* __restrict__ Alog,
        const float2* __restrict__ HB, const float* __restrict__ SDT,
        float* __restrict__ Y8T) {
    int w = (blockIdx.x << 2) + (threadIdx.x >> 6);   // [0, 3*BDW)
    int lane = threadIdx.x & 63;
    int cm1 = w >> 11;           // 0..2 -> chunk c = cm1+1
    int bd = w & (BDW - 1);
    int b = bd >> 10, d = bd & (DD - 1);
    float Av = -__expf(Alog[(size_t)d * NN + lane]);
    float2 h0 = HB[(size_t)bd * NN + lane];
    float hr = h0.x, hi = h0.y;
    if (cm1 >= 1) {
        float2 h1 = HB[((size_t)1 * BDW + bd) * NN + lane];
        float P1 = __expf(Av * SDT[1 * BDW + bd]);
        hr = fmaf(P1, hr, h1.x); hi = fmaf(P1, hi, h1.y);
        if (cm1 >= 2) {
            float2 h2 = HB[((size_t)2 * BDW + bd) * NN + lane];
            float P2 = __expf(Av * SDT[2 * BDW + bd]);
            hr = fmaf(P2, hr, h2.x); hi = fmaf(P2, hi, h2.y);
        }
    }
    int s0 = (cm1 + 1) * LC;
    size_t mBase = (size_t)(b << 10);
    size_t md = (mBase + s0) * DD + d;
    const float* ccp = BC2 + ((mBase + s0) * 64 + lane) * 4 + 2;
    size_t ys = (size_t)bd * SS + s0;
    size_t po = (size_t)(lane >> 4) * 2 * PS;
    for (int t = 0; t < LC; t += 4) {
        float4 yrq, yiq;
        #pragma unroll
        for (int k = 0; k < 4; ++k) {
            float dt = DT[md];
            float2 cc = *(const float2*)(ccp + (size_t)k * 256);
            float g = __expf(dt * Av);
            hr *= g; hi *= g;
            float pr = rsum16_dpp(hr * cc.x - hi * cc.y);
            float pi = rsum16_dpp(hr * cc.y + hi * cc.x);
            if (k == 0)      { yrq.x = pr; yiq.x = pi; }
            else if (k == 1) { yrq.y = pr; yiq.y = pi; }
            else if (k == 2) { yrq.z = pr; yiq.z = pi; }
            else             { yrq.w = pr; yiq.w = pi; }
            md += DD;
        }
        ccp += 1024;
        if ((lane & 15) == 15) {
            float4 orq = *(float4*)(Y8T + po + ys);
            float4 oiq = *(float4*)(Y8T + po + PS + ys);
            orq.x += yrq.x; orq.y += yrq.y; orq.z += yrq.z; orq.w += yrq.w;
            oiq.x += yiq.x; oiq.y += yiq.y; oiq.z += yiq.z; oiq.w += yiq.w;
            *(float4*)(Y8T + po + ys)      = orq;
            *(float4*)(Y8T + po + PS + ys) = oiq;
        }
        ys += 4;
    }
}

// ---------------- K6: y = (sum Y8T partials + Dk*x1) * csilu(z) -> f16 hi/lo ----------------
__global__ __launch_bounds__(256) void k_ymod(const float* __restrict__ Y8T,
        const float* __restrict__ X, const float* __restrict__ ZUr,
        const float* __restrict__ ZUi, const float* __restrict__ Dk,
        _Float16* __restrict__ YOh, _Float16* __restrict__ YOl) {
    __shared__ float tr[64][65];
    __shared__ float ti[64][65];
    int d0 = blockIdx.x * 64, m0 = blockIdx.y * 64;
    int b = m0 >> 10, s0 = m0 & (SS - 1);
    int t = threadIdx.x;
    int rr = t >> 2, c0 = (t & 3) * 4;
    size_t ybase = (size_t)(b * DD + d0 + rr) * SS + s0;
    #pragma unroll
    for (int j = 0; j < 4; ++j) {
        size_t o = ybase + c0 + j * 16;
        float4 r0 = *(const float4*)(Y8T + o);
        float4 r1 = *(const float4*)(Y8T + 2 * PS + o);
        float4 r2 = *(const float4*)(Y8T + 4 * PS + o);
        float4 r3 = *(const float4*)(Y8T + 6 * PS + o);
        float4 i0 = *(const float4*)(Y8T + PS + o);
        float4 i1 = *(const float4*)(Y8T + 3 * PS + o);
        float4 i2 = *(const float4*)(Y8T + 5 * PS + o);
        float4 i3 = *(const float4*)(Y8T + 7 * PS + o);
        float4 vr, vi;
        vr.x = (r3.x + r2.x) + (r1.x + r0.x);
        vr.y = (r3.y + r2.y) + (r1.y + r0.y);
        vr.z = (r3.z + r2.z) + (r1.z + r0.z);
        vr.w = (r3.w + r2.w) + (r1.w + r0.w);
        vi.x = (i3.x + i2.x) + (i1.x + i0.x);
        vi.y = (i3.y + i2.y) + (i1.y + i0.y);
        vi.z = (i3.z + i2.z) + (i1.z + i0.z);
        vi.w = (i3.w + i2.w) + (i1.w + i0.w);
        int sl = c0 + j * 16;
        tr[sl + 0][rr] = vr.x; tr[sl + 1][rr] = vr.y; tr[sl + 2][rr] = vr.z; tr[sl + 3][rr] = vr.w;
        ti[sl + 0][rr] = vi.x; ti[sl + 1][rr] = vi.y; ti[sl + 2][rr] = vi.z; ti[sl + 3][rr] = vi.w;
    }
    __syncthreads();
    int td = t & 63, tq = t >> 6;
    float dk = Dk[d0 + td];
    #pragma unroll
    for (int k = 0; k < 16; ++k) {
        int tm = tq * 16 + k;
        size_t i = (size_t)(m0 + tm) * DD + d0 + td;
        float yr = tr[tm][td];
        float yi = ti[tm][td];
        yr = fmaf(dk, X[i], yr);
        yi = fmaf(dk, X[PS + i], yi);
        float zr = ZUr[i], zi = ZUi[i];
        float or_ = yr * zr - yi * zi;
        float oi_ = yr * zi + yi * zr;
        _Float16 h0 = (_Float16)or_, h1 = (_Float16)oi_;
        YOh[i] = h0;      YOl[i] = (_Float16)(or_ - (float)h0);
        YOh[PS + i] = h1; YOl[PS + i] = (_Float16)(oi_ - (float)h1);
    }
}

// ---------------- K8: fused proj + correct (wave per row) ----------------
__global__ __launch_bounds__(256) void k_projcorr(float* __restrict__ BR,
        const float* __restrict__ Lop) {
    int row = (blockIdx.x << 2) + (threadIdx.x >> 6);
    int lane = threadIdx.x & 63;
    float* br = BR + (size_t)row * DD;
    float4 v[4], lw[4][4];
    float acc[4] = {0.f, 0.f, 0.f, 0.f};
    #pragma unroll
    for (int j = 0; j < 4; ++j) {
        int col = lane * 4 + j * 256;
        v[j] = *(const float4*)(br + col);
        #pragma unroll
        for (int k = 0; k < 4; ++k) {
            lw[j][k] = *(const float4*)(Lop + (size_t)k * DD + col);
            acc[k] += v[j].x * lw[j][k].x + v[j].y * lw[j][k].y
                    + v[j].z * lw[j][k].z + v[j].w * lw[j][k].w;
        }
    }
    #pragma unroll
    for (int off = 1; off <= 32; off <<= 1) {
        #pragma unroll
        for (int k = 0; k < 4; ++k) acc[k] += __shfl_xor(acc[k], off, 64);
    }
    #pragma unroll
    for (int j = 0; j < 4; ++j) {
        int col = lane * 4 + j * 256;
        float4 o;
        o.x = v[j].x - GAMMA_F * (acc[0]*lw[j][0].x + acc[1]*lw[j][1].x + acc[2]*lw[j][2].x + acc[3]*lw[j][3].x);
        o.y = v[j].y - GAMMA_F * (acc[0]*lw[j][0].y + acc[1]*lw[j][1].y + acc[2]*lw[j][2].y + acc[3]*lw[j][3].y);
        o.z = v[j].z - GAMMA_F * (acc[0]*lw[j][0].z + acc[1]*lw[j][1].z + acc[2]*lw[j][2].z + acc[3]*lw[j][3].z);
        o.w = v[j].w - GAMMA_F * (acc[0]*lw[j][0].w + acc[1]*lw[j][1].w + acc[2]*lw[j][2].w + acc[3]*lw[j][3].w);
        *(float4*)(br + col) = o;
    }
}

// ---------------- K9b: diag ----------------
__global__ __launch_bounds__(256) void k_diag(const float* __restrict__ BR,
        float* __restrict__ DG_) {
    __shared__ float red[4][64];
    int b = blockIdx.y, d0 = blockIdx.x * 64;
    int sg = threadIdx.x >> 6, ld = threadIdx.x & 63;
    float acc = 0.f;
    for (int s = sg; s < SS; s += 4) {
        size_t m = (size_t)(b * SS + s) * DD + d0 + ld;
        float r = BR[m], ii = BR[PS + m];
        acc = fmaf(r, r, fmaf(ii, ii, acc));
    }
    red[sg][ld] = acc;
    __syncthreads();
    if (threadIdx.x < 64) {
        float v = red[0][threadIdx.x] + red[1][threadIdx.x] + red[2][threadIdx.x] + red[3][threadIdx.x];
        DG_[b * DD + d0 + threadIdx.x] = v * (1.f / SS);
    }
}

// ---------------- K10: phase ----------------
__global__ __launch_bounds__(256) void k_phase(const float* __restrict__ DG_,
        float* __restrict__ PH) {
    __shared__ float mx[256], mn[256];
    int b = blockIdx.x;
    float vmax = -1e30f, vmin = 1e30f;
    for (int d = threadIdx.x; d < DD; d += 256) {
        float v = DG_[b * DD + d];
        vmax = fmaxf(vmax, v); vmin = fminf(vmin, v);
    }
    mx[threadIdx.x] = vmax; mn[threadIdx.x] = vmin;
    __syncthreads();
    for (int st = 128; st >= 1; st >>= 1) {
        if (threadIdx.x < st) {
            mx[threadIdx.x] = fmaxf(mx[threadIdx.x], mx[threadIdx.x + st]);
            mn[threadIdx.x] = fminf(mn[threadIdx.x], mn[threadIdx.x + st]);
        }
        __syncthreads();
    }
    if (threadIdx.x == 0) {
        float cond = mx[0] / (mn[0] + 1e-8f);
        bool ap = cond > 100.0f;
        PH[b * 2 + 0] = ap ? PHASE_COS : 1.f;
        PH[b * 2 + 1] = ap ? PHASE_SIN : 0.f;
    }
}

// ---------------- K11: residual + psi f16 split (x4 vec) ----------------
__global__ __launch_bounds__(256) void k_resid(float* __restrict__ Pr,
        float* __restrict__ Pi, const float* __restrict__ BR,
        const float* __restrict__ PH,
        _Float16* __restrict__ Ph, _Float16* __restrict__ Pl) {
    size_t i = ((size_t)blockIdx.x * 256 + threadIdx.x) * 4;
    int b = (int)(i >> 20);
    float pr = PH[b * 2], pih = PH[b * 2 + 1];
    float4 brr4 = *(const float4*)(BR + i);
    float4 bri4 = *(const float4*)(BR + PS + i);
    float4 pr4  = *(const float4*)(Pr + i);
    float4 pi4  = *(const float4*)(Pi + i);
    float brr[4] = {brr4.x, brr4.y, brr4.z, brr4.w};
    float bri[4] = {bri4.x, bri4.y, bri4.z, bri4.w};
    float pro[4] = {pr4.x, pr4.y, pr4.z, pr4.w};
    float pio[4] = {pi4.x, pi4.y, pi4.z, pi4.w};
    f16x4 rh, rl, ih, il;
    float nr[4], ni[4];
    #pragma unroll
    for (int c = 0; c < 4; ++c) {
        nr[c] = fmaf(SCALE_F, brr[c] * pr - bri[c] * pih, pro[c]);
        ni[c] = fmaf(SCALE_F, brr[c] * pih + bri[c] * pr, pio[c]);
        _Float16 h0 = (_Float16)nr[c]; rh[c] = h0; rl[c] = (_Float16)(nr[c] - (float)h0);
        _Float16 h1 = (_Float16)ni[c]; ih[c] = h1; il[c] = (_Float16)(ni[c] - (float)h1);
    }
    *(float4*)(Pr + i) = make_float4(nr[0], nr[1], nr[2], nr[3]);
    *(float4*)(Pi + i) = make_float4(ni[0], ni[1], ni[2], ni[3]);
    *(f16x4*)(Ph + i) = rh;      *(f16x4*)(Pl + i) = rl;
    *(f16x4*)(Ph + PS + i) = ih; *(f16x4*)(Pl + PS + i) = il;
}

// ---------------- K12: RMS norm -> f16 hi/lo split planes ----------------
__global__ __launch_bounds__(256) void k_rms(const float* __restrict__ Pr,
        const float* __restrict__ Pi, const float* __restrict__ nw,
        _Float16* __restrict__ Sp) {   // Sp: Rh | Rl | Ih | Il
    __shared__ float red[256];
    int m = blockIdx.x;
    int d = threadIdx.x * 4;
    float4 r  = *(const float4*)(Pr + (size_t)m * DD + d);
    float4 ii = *(const float4*)(Pi + (size_t)m * DD + d);
    float acc = r.x*r.x + r.y*r.y + r.z*r.z + r.w*r.w
              + ii.x*ii.x + ii.y*ii.y + ii.z*ii.z + ii.w*ii.w;
    red[threadIdx.x] = acc;
    __syncthreads();
    for (int st = 128; st >= 1; st >>= 1) {
        if (threadIdx.x < st) red[threadIdx.x] += red[threadIdx.x + st];
        __syncthreads();
    }
    float inv = 1.f / sqrtf(red[0] * (1.f / DD) + 1e-8f);
    float4 w = *(const float4*)(nw + d);
    float qr[4] = {r.x*inv*w.x, r.y*inv*w.y, r.z*inv*w.z, r.w*inv*w.w};
    float qi[4] = {ii.x*inv*w.x, ii.y*inv*w.y, ii.z*inv*w.z, ii.w*inv*w.w};
    f16x4 rh, rl, ih, il;
    #pragma unroll
    for (int j = 0; j < 4; ++j) {
        _Float16 h = (_Float16)qr[j]; rh[j] = h; rl[j] = (_Float16)(qr[j] - (float)h);
        _Float16 g = (_Float16)qi[j]; ih[j] = g; il[j] = (_Float16)(qi[j] - (float)g);
    }
    size_t o = (size_t)m * DD + d;
    *(f16x4*)(Sp + o)          = rh;
    *(f16x4*)(Sp + PS + o)     = rl;
    *(f16x4*)(Sp + 2 * PS + o) = ih;
    *(f16x4*)(Sp + 3 * PS + o) = il;
}

// ---------------- K12b: split emb_r f32 -> f16 hi/lo ----------------
__global__ __launch_bounds__(256) void k_split_e(const float* __restrict__ E,
        _Float16* __restrict__ Eh, _Float16* __restrict__ El) {
    size_t i = (size_t)(blockIdx.x * 256 + threadIdx.x) * 8;
    float4 a = *(const float4*)(E + i);
    float4 b = *(const float4*)(E + i + 4);
    float v[8] = {a.x, a.y, a.z, a.w, b.x, b.y, b.z, b.w};
    f16x8 hi, lo;
    #pragma unroll
    for (int j = 0; j < 8; ++j) {
        _Float16 h = (_Float16)v[j];
        hi[j] = h; lo[j] = (_Float16)(v[j] - (float)h);
    }
    *(f16x8*)(Eh + i) = hi;
    *(f16x8*)(El + i) = lo;
}

// ---------------- K13: MFMA f16-split logits GEMM, B direct from L2 ----------------
// K13 was LDS-BW bound (per CU/chunk: 288KB LDS / 128B/cy = 2250cy vs 932cy
// MFMA -> the measured 42% MfmaUtil). B (E-tiles) now loads global->VGPR
// directly: LDS drops to 192KB/chunk (A only) -> ceiling ~62%. B-tile is
// 16KB/block/chunk, shared by wave pairs (wv) via L1; L2 traffic ~32KB/chunk/CU
// << L2 BW. B loads issue before the A-barrier (full phase of latency cover).
// Math order identical -> bit-identical output.
// XCD-pinned mapping unchanged: XCD x owns m-tiles {2x, 2x+1}.
__global__ __launch_bounds__(256, 2) void k_logits_mfma(
        const _Float16* __restrict__ Sp,   // Rh|Rl|Ih|Il planes
        const _Float16* __restrict__ Eh, const _Float16* __restrict__ El,
        float* __restrict__ out) {
    __shared__ __align__(16) unsigned char lds[32768];
    const int lane = threadIdx.x & 63;
    const int wid  = threadIdx.x >> 6;
    const int wm = (wid >> 1) * 64;
    const int wv = (wid & 1) * 64;
    const int fr = lane & 15, fq = lane >> 4;
    int x = blockIdx.x & 7;
    int j = blockIdx.x >> 3;
    const int m0 = ((x << 1) | (j & 1)) << 7;
    const int v0 = (j >> 1) << 7;

    f32x4 accR[4][4] = {};
    f32x4 accI[4][4] = {};

    // per-lane B row base (row varies with fr, k-offset with fq)
    const size_t bofs = (size_t)(v0 + wv + fr) * DD + fq * 8;
    const _Float16* ehp = Eh + bofs;
    const _Float16* elp = El + bofs;

    for (int k0 = 0; k0 < DD; k0 += 32) {
        // A staging: 32 subtiles (4 planes x 8 rowblocks), 8 issues/wave
        #pragma unroll
        for (int jj = 0; jj < 8; ++jj) {
            int cid = jj * 4 + wid;
            int p = cid >> 3, c = cid & 7;
            const _Float16* src = Sp + (size_t)p * PS
                + (size_t)(m0 + c * 16 + fr) * DD + k0 + fq * 8;
            async16(lds + p * 8192 + c * 1024, src);
        }
        // B fragments direct to registers (overlaps with A staging latency)
        f16x8 bh[4], bl[4];
        #pragma unroll
        for (int vs = 0; vs < 4; ++vs) {
            bh[vs] = *(const f16x8*)(ehp + (size_t)vs * 16 * DD + k0);
            bl[vs] = *(const f16x8*)(elp + (size_t)vs * 16 * DD + k0);
        }
        __syncthreads();

        f16x8 aRh[4], aRl[4], aIh[4], aIl[4];
        #pragma unroll
        for (int ms = 0; ms < 4; ++ms) {
            int off = ((wm >> 4) + ms) * 1024 + lane * 16;
            aRh[ms] = *(const f16x8*)(lds + off);
            aRl[ms] = *(const f16x8*)(lds + 8192 + off);
            aIh[ms] = *(const f16x8*)(lds + 16384 + off);
            aIl[ms] = *(const f16x8*)(lds + 24576 + off);
        }
        #pragma unroll
        for (int vs = 0; vs < 4; ++vs) {
            #pragma unroll
            for (int ms = 0; ms < 4; ++ms) {
                accR[ms][vs] = __builtin_amdgcn_mfma_f32_16x16x32_f16(aRh[ms], bh[vs], accR[ms][vs], 0, 0, 0);
                accR[ms][vs] = __builtin_amdgcn_mfma_f32_16x16x32_f16(aRh[ms], bl[vs], accR[ms][vs], 0, 0, 0);
                accR[ms][vs] = __builtin_amdgcn_mfma_f32_16x16x32_f16(aRl[ms], bh[vs], accR[ms][vs], 0, 0, 0);
                accI[ms][vs] = __builtin_amdgcn_mfma_f32_16x16x32_f16(aIh[ms], bh[vs], accI[ms][vs], 0, 0, 0);
                accI[ms][vs] = __builtin_amdgcn_mfma_f32_16x16x32_f16(aIh[ms], bl[vs], accI[ms][vs], 0, 0, 0);
                accI[ms][vs] = __builtin_amdgcn_mfma_f32_16x16x32_f16(aIl[ms], bh[vs], accI[ms][vs], 0, 0, 0);
            }
        }
        __syncthreads();
    }

    #pragma unroll
    for (int ms = 0; ms < 4; ++ms) {
        #pragma unroll
        for (int vs = 0; vs < 4; ++vs) {
            #pragma unroll
            for (int r = 0; r < 4; ++r) {
                int row = m0 + wm + ms * 16 + fq * 4 + r;
                int col = v0 + wv + vs * 16 + fr;
                float ar = accR[ms][vs][r], ai = accI[ms][vs][r];
                out[(size_t)row * VV + col] = logf(fmaf(ar, ar, fmaf(ai, ai, 1e-8f)));
            }
        }
    }
}

extern "C" void kernel_launch(void* const* d_in, const int* in_sizes, int n_in,
                              void* d_out, int out_size, void* d_ws, size_t ws_size,
                              hipStream_t stream) {
    const int*   tok  = (const int*)d_in[0];
    const float* er   = (const float*)d_in[1];
    const float* ei   = (const float*)d_in[2];
    const float* Win  = (const float*)d_in[3];
    const float* ck   = (const float*)d_in[4];
    const float* Alog = (const float*)d_in[5];
    const float* dts  = (const float*)d_in[6];
    const float* dtb  = (const float*)d_in[7];
    const float* WB   = (const float*)d_in[8];
    const float* WC   = (const float*)d_in[9];
    const float* Dk   = (const float*)d_in[10];
    const float* Wo   = (const float*)d_in[11];
    const float* Lop  = (const float*)d_in[12];
    const float* nw   = (const float*)d_in[13];
    float* out = (float*)d_out;

    float* W0   = (float*)d_ws;
    float* P    = W0;                 // planes 0,1: psi f32
    float* XZ   = W0 + 2 * PS;        // planes 2..5 (layer phase)
    float* X    = W0 + 6 * PS;        // planes 6,7
    float* DTp  = W0 + 8 * PS;        // plane 8
    float* ZU   = W0 + 9 * PS;        // planes 9,10
    float* Y8T  = W0 + 11 * PS;       // planes 11..18 (8 partial planes, [g][bd][s])
    _Float16* YOh = (_Float16*)(W0 + 19 * PS);
    _Float16* YOl = (_Float16*)(W0 + 20 * PS);
    _Float16* Ph  = (_Float16*)(W0 + 21 * PS);
    _Float16* Pl  = (_Float16*)(W0 + 22 * PS);
    float* BR   = XZ;                 // alias planes 2,3
    // small arrays: planes 23,24
    float* BC2  = W0 + 23 * PS;                    // MM*64*4 floats (2MB)
    float* DIAG = BC2 + (size_t)MM * 64 * 4;
    float* PH   = DIAG + BB * DD;
    float2* HB  = (float2*)(PH + 16);              // CH*BDW*NN float2 (4MB)
    float* SDT  = (float*)(HB + (size_t)CH * BDW * NN);
    // weight splits (transposed): planes 25..30
    _Float16* Winh = (_Float16*)(W0 + 25 * PS);
    _Float16* Winl = (_Float16*)(W0 + 27 * PS);
    _Float16* Woh  = (_Float16*)(W0 + 29 * PS);
    _Float16* Wol  = (_Float16*)(W0 + 30 * PS);
    // end phase (layer buffers dead)
    _Float16* Sp  = (_Float16*)(W0 + 2 * PS);
    _Float16* Ehp = (_Float16*)(W0 + 4 * PS);
    _Float16* Elp = (_Float16*)(W0 + 13 * PS);

    k_split_w<<<dim3(32, 64, 4), 256, 0, stream>>>(Win, Winh, Winl, 1024, 2048);
    k_split_w<<<dim3(32, 32, 4), 256, 0, stream>>>(Wo, Woh, Wol, 1024, 1024);

    k_embed<<<(int)(PS / 4 / 256), 256, 0, stream>>>(tok, er, ei, P, P + PS, Ph, Pl);

    for (int l = 0; l < LLAYERS; ++l) {
        const float* Lopl = Lop + (size_t)l * KLL * DD;
        const float* Alogl = Alog + (size_t)l * DD * NN;
        const _Float16* Wih = Winh + (size_t)l * 2048 * 1024;
        const _Float16* Wil = Winl + (size_t)l * 2048 * 1024;
        const _Float16* Wohl = Woh + (size_t)l * 1024 * 1024;
        const _Float16* Woll = Wol + (size_t)l * 1024 * 1024;

        k_gemm_f16<<<dim3(2048 / 128, M2 / 128), 256, 0, stream>>>(Ph, Pl, Wih, Wil, XZ, 2048);
        k_conv<<<(int)(MM * (size_t)DD / 4 / 256), 256, 0, stream>>>(XZ, ck + (size_t)l * DD * KCC,
                dts + l * DD, dtb + l * DD, X, X + PS, DTp, ZU, ZU + PS);
        k_bc<<<M2 / 4, 256, 0, stream>>>(X, WB + (size_t)l * NN * DD, WC + (size_t)l * NN * DD, BC2);
        k_scan1<<<(BDW * CH) / 4, 256, 0, stream>>>(X, DTp, (const float4*)BC2, Alogl, Y8T, HB, SDT);
        k_scan3<<<(BDW * 3) / 4, 256, 0, stream>>>(DTp, BC2, Alogl, HB, SDT, Y8T);
        k_ymod<<<dim3(DD / 64, MM / 64), 256, 0, stream>>>(Y8T, X, ZU, ZU + PS, Dk + l * DD, YOh, YOl);
        k_gemm_n64<<<dim3(1024 / 64, M2 / 128), 256, 0, stream>>>(YOh, YOl, Wohl, Woll, BR, 1024);
        k_projcorr<<<M2 / 4, 256, 0, stream>>>(BR, Lopl);
        k_diag<<<dim3(DD / 64, BB), 256, 0, stream>>>(BR, DIAG);
        k_phase<<<BB, 256, 0, stream>>>(DIAG, PH);
        k_resid<<<(int)(PS / 4 / 256), 256, 0, stream>>>(P, P + PS, BR, PH, Ph, Pl);
    }

    k_rms<<<MM, 256, 0, stream>>>(P, P + PS, nw, Sp);
    k_split_e<<<(int)((size_t)VV * DD / 8 / 256), 256, 0, stream>>>(er, Ehp, Elp);
    k_logits_mfma<<<4000, 256, 0, stream>>>(Sp, Ehp, Elp, out);
}

// Round 12
// 3193.424 us; speedup vs baseline: 1.1081x; 1.1081x over previous
//
#include <hip/hip_runtime.h>
#include <math.h>

#define BB 2
#define SS 1024
#define DD 1024
#define NN 64
#define LLAYERS 4
#define KCC 4
#define KLL 4
#define VV 32000
#define MM (BB*SS)          // 2048
#define M2 (2*MM)           // 4096
#define PS ((size_t)MM*DD)  // 2097152 floats per plane
#define CH 4                // time chunks for scan
#define LC (SS/CH)          // 256 steps per chunk
#define BDW (BB*DD)         // 2048 (b,d) pairs

#define SCALE_F 0.35355339059327373f
#define GAMMA_F 0.01f
#define PHASE_COS 0.99500416527802576f
#define PHASE_SIN 0.09983341664682815f

typedef _Float16 f16x8 __attribute__((ext_vector_type(8)));
typedef _Float16 f16x4 __attribute__((ext_vector_type(4)));
typedef float f32x4 __attribute__((ext_vector_type(4)));

__device__ __forceinline__ float softplus_f(float x) {
    return fmaxf(x, 0.f) + log1pf(expf(-fabsf(x)));
}

__device__ __forceinline__ void async16(void* lds_dst, const void* g_src) {
    __builtin_amdgcn_global_load_lds(
        (const __attribute__((address_space(1))) unsigned int*)g_src,
        (__attribute__((address_space(3))) unsigned int*)lds_dst,
        16, 0, 0);
}

// 16-lane row-sum (VALU DPP row_shr tree). Partial sum valid in lane 15 mod 16.
__device__ __forceinline__ float rsum16_dpp(float v) {
    int x;
    x = __float_as_int(v);
    v += __int_as_float(__builtin_amdgcn_update_dpp(0, x, 0x111, 0xf, 0xf, true));
    x = __float_as_int(v);
    v += __int_as_float(__builtin_amdgcn_update_dpp(0, x, 0x112, 0xf, 0xf, true));
    x = __float_as_int(v);
    v += __int_as_float(__builtin_amdgcn_update_dpp(0, x, 0x114, 0xf, 0xf, true));
    x = __float_as_int(v);
    v += __int_as_float(__builtin_amdgcn_update_dpp(0, x, 0x118, 0xf, 0xf, true));
    return v;
}

// ---------------- K0: transpose + f16 hi/lo split of weights ----------------
__global__ __launch_bounds__(256) void k_split_w(const float* __restrict__ W,
        _Float16* __restrict__ Wh, _Float16* __restrict__ Wl, int Ksz, int Nsz) {
    __shared__ float t[32][33];
    int k0 = blockIdx.x * 32, n0 = blockIdx.y * 32;
    size_t base = (size_t)blockIdx.z * Ksz * Nsz;
    int r = threadIdx.x >> 3, c4 = (threadIdx.x & 7) * 4;
    float4 v = *(const float4*)(W + base + (size_t)(k0 + r) * Nsz + n0 + c4);
    t[r][c4 + 0] = v.x; t[r][c4 + 1] = v.y; t[r][c4 + 2] = v.z; t[r][c4 + 3] = v.w;
    __syncthreads();
    f16x4 hi, lo;
    #pragma unroll
    for (int j = 0; j < 4; ++j) {
        float x = t[c4 + j][r];
        _Float16 h = (_Float16)x;
        hi[j] = h; lo[j] = (_Float16)(x - (float)h);
    }
    size_t o = base + (size_t)(n0 + r) * Ksz + k0 + c4;
    *(f16x4*)(Wh + o) = hi;
    *(f16x4*)(Wl + o) = lo;
}

// ---------------- K1: embedding gather + psi f16 split ----------------
__global__ __launch_bounds__(256) void k_embed(const int* __restrict__ tok,
        const float* __restrict__ er, const float* __restrict__ ei,
        float* __restrict__ Pr, float* __restrict__ Pi,
        _Float16* __restrict__ Ph, _Float16* __restrict__ Pl) {
    int i = blockIdx.x * 256 + threadIdx.x;      // over PS/4
    int d4 = (i & (DD/4 - 1)) * 4;
    int m  = i >> 8;
    int t = tok[m];
    float4 r  = *(const float4*)(er + (size_t)t * DD + d4);
    float4 im = *(const float4*)(ei + (size_t)t * DD + d4);
    size_t o = (size_t)m * DD + d4;
    *(float4*)(Pr + o) = r;
    *(float4*)(Pi + o) = im;
    float vr[4] = {r.x, r.y, r.z, r.w}, vi[4] = {im.x, im.y, im.z, im.w};
    f16x4 rh, rl, ih, il;
    #pragma unroll
    for (int j = 0; j < 4; ++j) {
        _Float16 h = (_Float16)vr[j]; rh[j] = h; rl[j] = (_Float16)(vr[j] - (float)h);
        _Float16 g = (_Float16)vi[j]; ih[j] = g; il[j] = (_Float16)(vi[j] - (float)g);
    }
    *(f16x4*)(Ph + o) = rh;      *(f16x4*)(Pl + o) = rl;
    *(f16x4*)(Ph + PS + o) = ih; *(f16x4*)(Pl + PS + o) = il;
}

// ---------------- K2: f16-split MFMA GEMM: C(M2 x N) = A @ B^T ----------------
__global__ __launch_bounds__(256, 2) void k_gemm_f16(
        const _Float16* __restrict__ Ah, const _Float16* __restrict__ Al,
        const _Float16* __restrict__ Bh, const _Float16* __restrict__ Bl,
        float* __restrict__ C, int Nsz) {
    __shared__ __align__(16) unsigned char lds[32768];
    const int lane = threadIdx.x & 63;
    const int wid  = threadIdx.x >> 6;
    const int wm = (wid >> 1) * 64;
    const int wv = (wid & 1) * 64;
    const int n0 = blockIdx.x * 128;
    const int m0 = blockIdx.y * 128;
    const int fr = lane & 15, fq = lane >> 4;

    f32x4 acc[4][4] = {};

    for (int k0 = 0; k0 < 1024; k0 += 32) {
        #pragma unroll
        for (int j = 0; j < 8; ++j) {
            int cid = wid * 8 + j;
            int sel = cid >> 3, c = cid & 7;
            const _Float16* bp = (sel == 0) ? Ah : (sel == 1) ? Al : (sel == 2) ? Bh : Bl;
            int rbase = ((sel < 2) ? m0 : n0) + c * 16 + fr;
            async16(lds + cid * 1024, bp + (size_t)rbase * 1024 + k0 + fq * 8);
        }
        __syncthreads();

        f16x8 ah[4], al[4];
        #pragma unroll
        for (int ms = 0; ms < 4; ++ms) {
            int off = ((wm >> 4) + ms) * 1024 + lane * 16;
            ah[ms] = *(const f16x8*)(lds + off);
            al[ms] = *(const f16x8*)(lds + 8192 + off);
        }
        #pragma unroll
        for (int vs = 0; vs < 4; ++vs) {
            int boff = ((wv >> 4) + vs) * 1024 + lane * 16;
            f16x8 bh = *(const f16x8*)(lds + 16384 + boff);
            f16x8 bl = *(const f16x8*)(lds + 24576 + boff);
            #pragma unroll
            for (int ms = 0; ms < 4; ++ms) {
                acc[ms][vs] = __builtin_amdgcn_mfma_f32_16x16x32_f16(ah[ms], bh, acc[ms][vs], 0, 0, 0);
                acc[ms][vs] = __builtin_amdgcn_mfma_f32_16x16x32_f16(ah[ms], bl, acc[ms][vs], 0, 0, 0);
                acc[ms][vs] = __builtin_amdgcn_mfma_f32_16x16x32_f16(al[ms], bh, acc[ms][vs], 0, 0, 0);
            }
        }
        __syncthreads();
    }

    #pragma unroll
    for (int ms = 0; ms < 4; ++ms) {
        #pragma unroll
        for (int vs = 0; vs < 4; ++vs) {
            #pragma unroll
            for (int r = 0; r < 4; ++r) {
                int row = m0 + wm + ms * 16 + fq * 4 + r;
                int col = n0 + wv + vs * 16 + fr;
                C[(size_t)row * Nsz + col] = acc[ms][vs][r];
            }
        }
    }
}

// ---------------- K2b: 128x64-tile f16-split GEMM (N=1024 path) ----------------
__global__ __launch_bounds__(256, 2) void k_gemm_n64(
        const _Float16* __restrict__ Ah, const _Float16* __restrict__ Al,
        const _Float16* __restrict__ Bh, const _Float16* __restrict__ Bl,
        float* __restrict__ C, int Nsz) {
    __shared__ __align__(16) unsigned char lds[24576];
    const int lane = threadIdx.x & 63;
    const int wid  = threadIdx.x >> 6;
    const int wm = (wid >> 1) * 64;
    const int wv = (wid & 1) * 32;
    const int n0 = blockIdx.x * 64;
    const int m0 = blockIdx.y * 128;
    const int fr = lane & 15, fq = lane >> 4;

    f32x4 acc[4][2] = {};

    for (int k0 = 0; k0 < 1024; k0 += 32) {
        #pragma unroll
        for (int j = 0; j < 6; ++j) {
            int cid = j * 4 + wid;
            const _Float16* bp;
            int rbase, ldsoff;
            if (cid < 16) {           // A: plane cid>>3, 16-row subtile cid&7
                bp = (cid >> 3) ? Al : Ah;
                rbase = m0 + (cid & 7) * 16 + fr;
                ldsoff = cid * 1024;
            } else {                  // B: plane (cid-16)>>2, subtile (cid-16)&3
                int r = cid - 16;
                bp = (r >> 2) ? Bl : Bh;
                rbase = n0 + (r & 3) * 16 + fr;
                ldsoff = 16384 + r * 1024;
            }
            async16(lds + ldsoff, bp + (size_t)rbase * 1024 + k0 + fq * 8);
        }
        __syncthreads();

        f16x8 ah[4], al[4];
        #pragma unroll
        for (int ms = 0; ms < 4; ++ms) {
            int off = ((wm >> 4) + ms) * 1024 + lane * 16;
            ah[ms] = *(const f16x8*)(lds + off);
            al[ms] = *(const f16x8*)(lds + 8192 + off);
        }
        #pragma unroll
        for (int vs = 0; vs < 2; ++vs) {
            int boff = ((wv >> 4) + vs) * 1024 + lane * 16;
            f16x8 bh = *(const f16x8*)(lds + 16384 + boff);
            f16x8 bl = *(const f16x8*)(lds + 20480 + boff);
            #pragma unroll
            for (int ms = 0; ms < 4; ++ms) {
                acc[ms][vs] = __builtin_amdgcn_mfma_f32_16x16x32_f16(ah[ms], bh, acc[ms][vs], 0, 0, 0);
                acc[ms][vs] = __builtin_amdgcn_mfma_f32_16x16x32_f16(ah[ms], bl, acc[ms][vs], 0, 0, 0);
                acc[ms][vs] = __builtin_amdgcn_mfma_f32_16x16x32_f16(al[ms], bh, acc[ms][vs], 0, 0, 0);
            }
        }
        __syncthreads();
    }

    #pragma unroll
    for (int ms = 0; ms < 4; ++ms) {
        #pragma unroll
        for (int vs = 0; vs < 2; ++vs) {
            #pragma unroll
            for (int r = 0; r < 4; ++r) {
                int row = m0 + wm + ms * 16 + fq * 4 + r;
                int col = n0 + wv + vs * 16 + fr;
                C[(size_t)row * Nsz + col] = acc[ms][vs][r];
            }
        }
    }
}

// ---------------- K3: causal depthwise conv + csilu + dt + z-gate (x4 vec) ----------------
__global__ __launch_bounds__(256) void k_conv(const float* __restrict__ XZ,
        const float* __restrict__ ck, const float* __restrict__ dts,
        const float* __restrict__ dtb,
        float* __restrict__ Xr, float* __restrict__ Xi, float* __restrict__ DT,
        float* __restrict__ ZUr, float* __restrict__ ZUi) {
    int i4 = blockIdx.x * 256 + threadIdx.x;     // over MM*DD/4
    int dq = (i4 & (DD / 4 - 1)) * 4;
    int m  = i4 >> 8;
    int b = m >> 10, s = m & (SS - 1);
    size_t i = (size_t)m * DD + dq;
    float kw[4][4];
    #pragma unroll
    for (int c = 0; c < 4; ++c)
        *(float4*)kw[c] = *(const float4*)(ck + (size_t)(dq + c) * KCC);
    float cr[4] = {0.f, 0.f, 0.f, 0.f}, ci[4] = {0.f, 0.f, 0.f, 0.f};
    #pragma unroll
    for (int j = 0; j < KCC; ++j) {
        int sj = s - (KCC - 1) + j;
        if (sj >= 0) {
            size_t mm = ((size_t)(b << 10) + sj) * 2048 + dq;
            float4 xr4 = *(const float4*)(XZ + mm);
            float4 xi4 = *(const float4*)(XZ + (size_t)MM * 2048 + mm);
            float xr_[4] = {xr4.x, xr4.y, xr4.z, xr4.w};
            float xi_[4] = {xi4.x, xi4.y, xi4.z, xi4.w};
            #pragma unroll
            for (int c = 0; c < 4; ++c) {
                cr[c] = fmaf(xr_[c], kw[c][j], cr[c]);
                ci[c] = fmaf(xi_[c], kw[c][j], ci[c]);
            }
        }
    }
    float4 dts4 = *(const float4*)(dts + dq);
    float4 dtb4 = *(const float4*)(dtb + dq);
    float dts_[4] = {dts4.x, dts4.y, dts4.z, dts4.w};
    float dtb_[4] = {dtb4.x, dtb4.y, dtb4.z, dtb4.w};
    float xro[4], xio[4], dto[4];
    #pragma unroll
    for (int c = 0; c < 4; ++c) {
        float mag = sqrtf(cr[c] * cr[c] + ci[c] * ci[c]);
        float sg = 1.f / (1.f + expf(-mag));
        xro[c] = cr[c] * sg; xio[c] = ci[c] * sg;
        dto[c] = softplus_f(fmaf(xro[c], dts_[c], dtb_[c]));
    }
    *(float4*)(Xr + i) = make_float4(xro[0], xro[1], xro[2], xro[3]);
    *(float4*)(Xi + i) = make_float4(xio[0], xio[1], xio[2], xio[3]);
    *(float4*)(DT + i) = make_float4(dto[0], dto[1], dto[2], dto[3]);
    float4 zr4 = *(const float4*)(XZ + (size_t)m * 2048 + DD + dq);
    float4 zi4 = *(const float4*)(XZ + (size_t)(MM + m) * 2048 + DD + dq);
    float zr_[4] = {zr4.x, zr4.y, zr4.z, zr4.w};
    float zi_[4] = {zi4.x, zi4.y, zi4.z, zi4.w};
    float zur[4], zui[4];
    #pragma unroll
    for (int c = 0; c < 4; ++c) {
        float mz = sqrtf(zr_[c] * zr_[c] + zi_[c] * zi_[c]);
        float sz = 1.f / (1.f + expf(-mz));
        zur[c] = zr_[c] * sz; zui[c] = zi_[c] * sz;
    }
    *(float4*)(ZUr + i) = make_float4(zur[0], zur[1], zur[2], zur[3]);
    *(float4*)(ZUi + i) = make_float4(zui[0], zui[1], zui[2], zui[3]);
}

// ---------------- K4: Bc/Cc projections -> packed BC2[(m*64+n)*4 + {br,bi,cr,ci}] ----------------
__global__ __launch_bounds__(256) void k_bc(const float* __restrict__ X,
        const float* __restrict__ WBp, const float* __restrict__ WCp,
        float* __restrict__ BC2) {
    __shared__ float xs[4][DD];
    __shared__ float red[4 * 256];
    int r0 = blockIdx.x * 4;
    for (int f = threadIdx.x; f < 4 * (DD / 4); f += 256) {
        int r = f / (DD / 4), c = (f % (DD / 4)) * 4;
        *(float4*)(&xs[r][c]) = *(const float4*)(X + (size_t)(r0 + r) * DD + c);
    }
    __syncthreads();
    int out = threadIdx.x & 127;
    int half = threadIdx.x >> 7;
    const float* Wrow = (out < 64) ? (WBp + (size_t)out * DD) : (WCp + (size_t)(out - 64) * DD);
    float acc[4] = {0.f, 0.f, 0.f, 0.f};
    for (int k = half * 512; k < half * 512 + 512; k += 4) {
        float4 w = *(const float4*)(Wrow + k);
        #pragma unroll
        for (int r = 0; r < 4; ++r) {
            float4 x4 = *(float4*)(&xs[r][k]);
            acc[r] = fmaf(x4.x, w.x, fmaf(x4.y, w.y, fmaf(x4.z, w.z, fmaf(x4.w, w.w, acc[r]))));
        }
    }
    #pragma unroll
    for (int r = 0; r < 4; ++r) red[r * 256 + threadIdx.x] = acc[r];
    __syncthreads();
    if (threadIdx.x < 128) {
        int isIm = (r0 >= MM) ? 1 : 0;
        int n = out & 63;
        int comp = ((out >> 6) << 1) | isIm;   // br=0, bi=1, cr=2, ci=3
        #pragma unroll
        for (int r = 0; r < 4; ++r) {
            float v = red[r * 256 + threadIdx.x] + red[r * 256 + threadIdx.x + 128];
            int m = (r0 + r) & (MM - 1);
            BC2[((size_t)m * 64 + n) * 4 + comp] = v;
        }
    }
}

// ---------------- K3b: transpose DT/Xr/Xi -> [bd][s] for the scans ----------------
// Pure layout copy (ymod-pattern LDS tile transpose): scans then load these as
// one float4 per 4 steps instead of 12 stride-4KB scalar loads.
__global__ __launch_bounds__(256) void k_xpose(const float* __restrict__ A,
        const float* __restrict__ B, const float* __restrict__ C,
        float* __restrict__ At, float* __restrict__ Bt, float* __restrict__ Ct) {
    __shared__ float tile[64][65];
    int d0 = blockIdx.x * 64, m0 = blockIdx.y * 64;
    int b = m0 >> 10, s0 = m0 & (SS - 1);
    int tx = threadIdx.x & 63, ty = threadIdx.x >> 6;
    const float* in[3]  = {A, B, C};
    float* outp[3] = {At, Bt, Ct};
    #pragma unroll
    for (int p = 0; p < 3; ++p) {
        #pragma unroll
        for (int k = 0; k < 16; ++k) {
            int r = ty + 4 * k;
            tile[r][tx] = in[p][(size_t)(m0 + r) * DD + d0 + tx];
        }
        __syncthreads();
        #pragma unroll
        for (int k = 0; k < 16; ++k) {
            int d = ty + 4 * k;
            outp[p][(size_t)(b * DD + d0 + d) * SS + s0 + tx] = tile[tx][d];
        }
        __syncthreads();
    }
}

// ---------------- K5a: scan pass 1, 4-step unrolled, vectorized T-plane loads ----------------
// Y8T: 8 planes [g16*2 + {r,i}][bd][s]. DTt/XrT/XiT in [bd][s]: one float4
// load per array per 4 steps (wave-uniform, contiguous).
__global__ __launch_bounds__(256, 8) void k_scan1(const float* __restrict__ XrT,
        const float* __restrict__ XiT, const float* __restrict__ DTt,
        const float4* __restrict__ BC2,
        const float* __restrict__ Alog, float* __restrict__ Y8T,
        float2* __restrict__ HB, float* __restrict__ SDT) {
    int w = (blockIdx.x << 2) + (threadIdx.x >> 6);   // (bd, c)
    int lane = threadIdx.x & 63;
    int c = w & (CH - 1);
    int bd = w >> 2;
    int b = bd >> 10, d = bd & (DD - 1);
    float Av = -__expf(Alog[(size_t)d * NN + lane]);
    float hr = 0.f, hi = 0.f, sdt = 0.f;
    int s0 = c * LC;
    size_t mBase = (size_t)(b << 10);
    const float4* bcp = BC2 + (mBase + s0) * 64 + lane;
    size_t ys = (size_t)bd * SS + s0;
    size_t po = (size_t)(lane >> 4) * 2 * PS;
    for (int t = 0; t < LC; t += 4) {
        float4 dt4 = *(const float4*)(DTt + ys);
        float4 xr4 = *(const float4*)(XrT + ys);
        float4 xi4 = *(const float4*)(XiT + ys);
        float dtv[4] = {dt4.x, dt4.y, dt4.z, dt4.w};
        float xrv[4] = {xr4.x, xr4.y, xr4.z, xr4.w};
        float xiv[4] = {xi4.x, xi4.y, xi4.z, xi4.w};
        float4 yrq, yiq;
        #pragma unroll
        for (int k = 0; k < 4; ++k) {
            float4 bc = bcp[(size_t)k * 64];
            float g = __expf(dtv[k] * Av);
            float dxr = dtv[k] * xrv[k], dxi = dtv[k] * xiv[k];
            hr = fmaf(g, hr, fmaf(dxr, bc.x, -dxi * bc.y));
            hi = fmaf(g, hi, fmaf(dxr, bc.y,  dxi * bc.x));
            sdt += dtv[k];
            float pr = rsum16_dpp(hr * bc.z - hi * bc.w);
            float pi = rsum16_dpp(hr * bc.w + hi * bc.z);
            if (k == 0)      { yrq.x = pr; yiq.x = pi; }
            else if (k == 1) { yrq.y = pr; yiq.y = pi; }
            else if (k == 2) { yrq.z = pr; yiq.z = pi; }
            else             { yrq.w = pr; yiq.w = pi; }
        }
        bcp += 256;
        if ((lane & 15) == 15) {
            *(float4*)(Y8T + po + ys)      = yrq;
            *(float4*)(Y8T + po + PS + ys) = yiq;
        }
        ys += 4;
    }
    HB[((size_t)c * BDW + bd) * NN + lane] = make_float2(hr, hi);
    if (lane == 0) SDT[c * BDW + bd] = sdt;
}

// ---------------- K5c: inflow correction, 4-step unrolled, vectorized DT load ----------------
__global__ __launch_bounds__(256, 8) void k_scan3(const float* __restrict__ DTt,
        const float* __restrict__ BC2, const float* __restrict__ Alog,
        const float2* __restrict__ HB, const float* __restrict__ SDT,
        float* __restrict__ Y8T) {
    int w = (blockIdx.x << 2) + (threadIdx.x >> 6);   // [0, 3*BDW)
    int lane = threadIdx.x & 63;
    int cm1 = w >> 11;           // 0..2 -> chunk c = cm1+1
    int bd = w & (BDW - 1);
    int b = bd >> 10, d = bd & (DD - 1);
    float Av = -__expf(Alog[(size_t)d * NN + lane]);
    float2 h0 = HB[(size_t)bd * NN + lane];
    float hr = h0.x, hi = h0.y;
    if (cm1 >= 1) {
        float2 h1 = HB[((size_t)1 * BDW + bd) * NN + lane];
        float P1 = __expf(Av * SDT[1 * BDW + bd]);
        hr = fmaf(P1, hr, h1.x); hi = fmaf(P1, hi, h1.y);
        if (cm1 >= 2) {
            float2 h2 = HB[((size_t)2 * BDW + bd) * NN + lane];
            float P2 = __expf(Av * SDT[2 * BDW + bd]);
            hr = fmaf(P2, hr, h2.x); hi = fmaf(P2, hi, h2.y);
        }
    }
    int s0 = (cm1 + 1) * LC;
    size_t mBase = (size_t)(b << 10);
    const float* ccp = BC2 + ((mBase + s0) * 64 + lane) * 4 + 2;
    size_t ys = (size_t)bd * SS + s0;
    size_t po = (size_t)(lane >> 4) * 2 * PS;
    for (int t = 0; t < LC; t += 4) {
        float4 dt4 = *(const float4*)(DTt + ys);
        float dtv[4] = {dt4.x, dt4.y, dt4.z, dt4.w};
        float4 yrq, yiq;
        #pragma unroll
        for (int k = 0; k < 4; ++k) {
            float2 cc = *(const float2*)(ccp + (size_t)k * 256);
            float g = __expf(dtv[k] * Av);
            hr *= g; hi *= g;
            float pr = rsum16_dpp(hr * cc.x - hi * cc.y);
            float pi = rsum16_dpp(hr * cc.y + hi * cc.x);
            if (k == 0)      { yrq.x = pr; yiq.x = pi; }
            else if (k == 1) { yrq.y = pr; yiq.y = pi; }
            else if (k == 2) { yrq.z = pr; yiq.z = pi; }
            else             { yrq.w = pr; yiq.w = pi; }
        }
        ccp += 1024;
        if ((lane & 15) == 15) {
            float4 orq = *(float4*)(Y8T + po + ys);
            float4 oiq = *(float4*)(Y8T + po + PS + ys);
            orq.x += yrq.x; orq.y += yrq.y; orq.z += yrq.z; orq.w += yrq.w;
            oiq.x += yiq.x; oiq.y += yiq.y; oiq.z += yiq.z; oiq.w += yiq.w;
            *(float4*)(Y8T + po + ys)      = orq;
            *(float4*)(Y8T + po + PS + ys) = oiq;
        }
        ys += 4;
    }
}

// ---------------- K6: y = (sum Y8T partials + Dk*x1) * csilu(z) -> f16 hi/lo ----------------
__global__ __launch_bounds__(256) void k_ymod(const float* __restrict__ Y8T,
        const float* __restrict__ X, const float* __restrict__ ZUr,
        const float* __restrict__ ZUi, const float* __restrict__ Dk,
        _Float16* __restrict__ YOh, _Float16* __restrict__ YOl) {
    __shared__ float tr[64][65];
    __shared__ float ti[64][65];
    int d0 = blockIdx.x * 64, m0 = blockIdx.y * 64;
    int b = m0 >> 10, s0 = m0 & (SS - 1);
    int t = threadIdx.x;
    int rr = t >> 2, c0 = (t & 3) * 4;
    size_t ybase = (size_t)(b * DD + d0 + rr) * SS + s0;
    #pragma unroll
    for (int j = 0; j < 4; ++j) {
        size_t o = ybase + c0 + j * 16;
        float4 r0 = *(const float4*)(Y8T + o);
        float4 r1 = *(const float4*)(Y8T + 2 * PS + o);
        float4 r2 = *(const float4*)(Y8T + 4 * PS + o);
        float4 r3 = *(const float4*)(Y8T + 6 * PS + o);
        float4 i0 = *(const float4*)(Y8T + PS + o);
        float4 i1 = *(const float4*)(Y8T + 3 * PS + o);
        float4 i2 = *(const float4*)(Y8T + 5 * PS + o);
        float4 i3 = *(const float4*)(Y8T + 7 * PS + o);
        float4 vr, vi;
        vr.x = (r3.x + r2.x) + (r1.x + r0.x);
        vr.y = (r3.y + r2.y) + (r1.y + r0.y);
        vr.z = (r3.z + r2.z) + (r1.z + r0.z);
        vr.w = (r3.w + r2.w) + (r1.w + r0.w);
        vi.x = (i3.x + i2.x) + (i1.x + i0.x);
        vi.y = (i3.y + i2.y) + (i1.y + i0.y);
        vi.z = (i3.z + i2.z) + (i1.z + i0.z);
        vi.w = (i3.w + i2.w) + (i1.w + i0.w);
        int sl = c0 + j * 16;
        tr[sl + 0][rr] = vr.x; tr[sl + 1][rr] = vr.y; tr[sl + 2][rr] = vr.z; tr[sl + 3][rr] = vr.w;
        ti[sl + 0][rr] = vi.x; ti[sl + 1][rr] = vi.y; ti[sl + 2][rr] = vi.z; ti[sl + 3][rr] = vi.w;
    }
    __syncthreads();
    int td = t & 63, tq = t >> 6;
    float dk = Dk[d0 + td];
    #pragma unroll
    for (int k = 0; k < 16; ++k) {
        int tm = tq * 16 + k;
        size_t i = (size_t)(m0 + tm) * DD + d0 + td;
        float yr = tr[tm][td];
        float yi = ti[tm][td];
        yr = fmaf(dk, X[i], yr);
        yi = fmaf(dk, X[PS + i], yi);
        float zr = ZUr[i], zi = ZUi[i];
        float or_ = yr * zr - yi * zi;
        float oi_ = yr * zi + yi * zr;
        _Float16 h0 = (_Float16)or_, h1 = (_Float16)oi_;
        YOh[i] = h0;      YOl[i] = (_Float16)(or_ - (float)h0);
        YOh[PS + i] = h1; YOl[PS + i] = (_Float16)(oi_ - (float)h1);
    }
}

// ---------------- K8: fused proj + correct (wave per row) ----------------
__global__ __launch_bounds__(256) void k_projcorr(float* __restrict__ BR,
        const float* __restrict__ Lop) {
    int row = (blockIdx.x << 2) + (threadIdx.x >> 6);
    int lane = threadIdx.x & 63;
    float* br = BR + (size_t)row * DD;
    float4 v[4], lw[4][4];
    float acc[4] = {0.f, 0.f, 0.f, 0.f};
    #pragma unroll
    for (int j = 0; j < 4; ++j) {
        int col = lane * 4 + j * 256;
        v[j] = *(const float4*)(br + col);
        #pragma unroll
        for (int k = 0; k < 4; ++k) {
            lw[j][k] = *(const float4*)(Lop + (size_t)k * DD + col);
            acc[k] += v[j].x * lw[j][k].x + v[j].y * lw[j][k].y
                    + v[j].z * lw[j][k].z + v[j].w * lw[j][k].w;
        }
    }
    #pragma unroll
    for (int off = 1; off <= 32; off <<= 1) {
        #pragma unroll
        for (int k = 0; k < 4; ++k) acc[k] += __shfl_xor(acc[k], off, 64);
    }
    #pragma unroll
    for (int j = 0; j < 4; ++j) {
        int col = lane * 4 + j * 256;
        float4 o;
        o.x = v[j].x - GAMMA_F * (acc[0]*lw[j][0].x + acc[1]*lw[j][1].x + acc[2]*lw[j][2].x + acc[3]*lw[j][3].x);
        o.y = v[j].y - GAMMA_F * (acc[0]*lw[j][0].y + acc[1]*lw[j][1].y + acc[2]*lw[j][2].y + acc[3]*lw[j][3].y);
        o.z = v[j].z - GAMMA_F * (acc[0]*lw[j][0].z + acc[1]*lw[j][1].z + acc[2]*lw[j][2].z + acc[3]*lw[j][3].z);
        o.w = v[j].w - GAMMA_F * (acc[0]*lw[j][0].w + acc[1]*lw[j][1].w + acc[2]*lw[j][2].w + acc[3]*lw[j][3].w);
        *(float4*)(br + col) = o;
    }
}

// ---------------- K9b: diag ----------------
__global__ __launch_bounds__(256) void k_diag(const float* __restrict__ BR,
        float* __restrict__ DG_) {
    __shared__ float red[4][64];
    int b = blockIdx.y, d0 = blockIdx.x * 64;
    int sg = threadIdx.x >> 6, ld = threadIdx.x & 63;
    float acc = 0.f;
    for (int s = sg; s < SS; s += 4) {
        size_t m = (size_t)(b * SS + s) * DD + d0 + ld;
        float r = BR[m], ii = BR[PS + m];
        acc = fmaf(r, r, fmaf(ii, ii, acc));
    }
    red[sg][ld] = acc;
    __syncthreads();
    if (threadIdx.x < 64) {
        float v = red[0][threadIdx.x] + red[1][threadIdx.x] + red[2][threadIdx.x] + red[3][threadIdx.x];
        DG_[b * DD + d0 + threadIdx.x] = v * (1.f / SS);
    }
}

// ---------------- K10: phase ----------------
__global__ __launch_bounds__(256) void k_phase(const float* __restrict__ DG_,
        float* __restrict__ PH) {
    __shared__ float mx[256], mn[256];
    int b = blockIdx.x;
    float vmax = -1e30f, vmin = 1e30f;
    for (int d = threadIdx.x; d < DD; d += 256) {
        float v = DG_[b * DD + d];
        vmax = fmaxf(vmax, v); vmin = fminf(vmin, v);
    }
    mx[threadIdx.x] = vmax; mn[threadIdx.x] = vmin;
    __syncthreads();
    for (int st = 128; st >= 1; st >>= 1) {
        if (threadIdx.x < st) {
            mx[threadIdx.x] = fmaxf(mx[threadIdx.x], mx[threadIdx.x + st]);
            mn[threadIdx.x] = fminf(mn[threadIdx.x], mn[threadIdx.x + st]);
        }
        __syncthreads();
    }
    if (threadIdx.x == 0) {
        float cond = mx[0] / (mn[0] + 1e-8f);
        bool ap = cond > 100.0f;
        PH[b * 2 + 0] = ap ? PHASE_COS : 1.f;
        PH[b * 2 + 1] = ap ? PHASE_SIN : 0.f;
    }
}

// ---------------- K11: residual + psi f16 split (x4 vec) ----------------
__global__ __launch_bounds__(256) void k_resid(float* __restrict__ Pr,
        float* __restrict__ Pi, const float* __restrict__ BR,
        const float* __restrict__ PH,
        _Float16* __restrict__ Ph, _Float16* __restrict__ Pl) {
    size_t i = ((size_t)blockIdx.x * 256 + threadIdx.x) * 4;
    int b = (int)(i >> 20);
    float pr = PH[b * 2], pih = PH[b * 2 + 1];
    float4 brr4 = *(const float4*)(BR + i);
    float4 bri4 = *(const float4*)(BR + PS + i);
    float4 pr4  = *(const float4*)(Pr + i);
    float4 pi4  = *(const float4*)(Pi + i);
    float brr[4] = {brr4.x, brr4.y, brr4.z, brr4.w};
    float bri[4] = {bri4.x, bri4.y, bri4.z, bri4.w};
    float pro[4] = {pr4.x, pr4.y, pr4.z, pr4.w};
    float pio[4] = {pi4.x, pi4.y, pi4.z, pi4.w};
    f16x4 rh, rl, ih, il;
    float nr[4], ni[4];
    #pragma unroll
    for (int c = 0; c < 4; ++c) {
        nr[c] = fmaf(SCALE_F, brr[c] * pr - bri[c] * pih, pro[c]);
        ni[c] = fmaf(SCALE_F, brr[c] * pih + bri[c] * pr, pio[c]);
        _Float16 h0 = (_Float16)nr[c]; rh[c] = h0; rl[c] = (_Float16)(nr[c] - (float)h0);
        _Float16 h1 = (_Float16)ni[c]; ih[c] = h1; il[c] = (_Float16)(ni[c] - (float)h1);
    }
    *(float4*)(Pr + i) = make_float4(nr[0], nr[1], nr[2], nr[3]);
    *(float4*)(Pi + i) = make_float4(ni[0], ni[1], ni[2], ni[3]);
    *(f16x4*)(Ph + i) = rh;      *(f16x4*)(Pl + i) = rl;
    *(f16x4*)(Ph + PS + i) = ih; *(f16x4*)(Pl + PS + i) = il;
}

// ---------------- K12: RMS norm -> f16 hi/lo split planes ----------------
__global__ __launch_bounds__(256) void k_rms(const float* __restrict__ Pr,
        const float* __restrict__ Pi, const float* __restrict__ nw,
        _Float16* __restrict__ Sp) {   // Sp: Rh | Rl | Ih | Il
    __shared__ float red[256];
    int m = blockIdx.x;
    int d = threadIdx.x * 4;
    float4 r  = *(const float4*)(Pr + (size_t)m * DD + d);
    float4 ii = *(const float4*)(Pi + (size_t)m * DD + d);
    float acc = r.x*r.x + r.y*r.y + r.z*r.z + r.w*r.w
              + ii.x*ii.x + ii.y*ii.y + ii.z*ii.z + ii.w*ii.w;
    red[threadIdx.x] = acc;
    __syncthreads();
    for (int st = 128; st >= 1; st >>= 1) {
        if (threadIdx.x < st) red[threadIdx.x] += red[threadIdx.x + st];
        __syncthreads();
    }
    float inv = 1.f / sqrtf(red[0] * (1.f / DD) + 1e-8f);
    float4 w = *(const float4*)(nw + d);
    float qr[4] = {r.x*inv*w.x, r.y*inv*w.y, r.z*inv*w.z, r.w*inv*w.w};
    float qi[4] = {ii.x*inv*w.x, ii.y*inv*w.y, ii.z*inv*w.z, ii.w*inv*w.w};
    f16x4 rh, rl, ih, il;
    #pragma unroll
    for (int j = 0; j < 4; ++j) {
        _Float16 h = (_Float16)qr[j]; rh[j] = h; rl[j] = (_Float16)(qr[j] - (float)h);
        _Float16 g = (_Float16)qi[j]; ih[j] = g; il[j] = (_Float16)(qi[j] - (float)g);
    }
    size_t o = (size_t)m * DD + d;
    *(f16x4*)(Sp + o)          = rh;
    *(f16x4*)(Sp + PS + o)     = rl;
    *(f16x4*)(Sp + 2 * PS + o) = ih;
    *(f16x4*)(Sp + 3 * PS + o) = il;
}

// ---------------- K12b: split emb_r f32 -> f16 hi/lo ----------------
__global__ __launch_bounds__(256) void k_split_e(const float* __restrict__ E,
        _Float16* __restrict__ Eh, _Float16* __restrict__ El) {
    size_t i = (size_t)(blockIdx.x * 256 + threadIdx.x) * 8;
    float4 a = *(const float4*)(E + i);
    float4 b = *(const float4*)(E + i + 4);
    float v[8] = {a.x, a.y, a.z, a.w, b.x, b.y, b.z, b.w};
    f16x8 hi, lo;
    #pragma unroll
    for (int j = 0; j < 8; ++j) {
        _Float16 h = (_Float16)v[j];
        hi[j] = h; lo[j] = (_Float16)(v[j] - (float)h);
    }
    *(f16x8*)(Eh + i) = hi;
    *(f16x8*)(El + i) = lo;
}

// ---------------- K13: MFMA f16-split logits GEMM (round-9 form, best known) ----------------
// XCD-pinned mapping: XCD x owns m-tiles {2x, 2x+1} (A = 2MB, L2-resident);
// all XCDs sweep v in lockstep so each E-tile is L3-fetched once, read 16x.
__global__ __launch_bounds__(256, 2) void k_logits_mfma(
        const _Float16* __restrict__ Sp,   // Rh|Rl|Ih|Il planes
        const _Float16* __restrict__ Eh, const _Float16* __restrict__ El,
        float* __restrict__ out) {
    __shared__ __align__(16) unsigned char lds[49152];
    const int lane = threadIdx.x & 63;
    const int wid  = threadIdx.x >> 6;
    const int wm = (wid >> 1) * 64;
    const int wv = (wid & 1) * 64;
    const int fr = lane & 15, fq = lane >> 4;
    int x = blockIdx.x & 7;
    int j = blockIdx.x >> 3;
    const int m0 = ((x << 1) | (j & 1)) << 7;
    const int v0 = (j >> 1) << 7;

    f32x4 accR[4][4] = {};
    f32x4 accI[4][4] = {};

    for (int k0 = 0; k0 < DD; k0 += 32) {
        #pragma unroll
        for (int jj = 0; jj < 12; ++jj) {
            int cid = jj * 4 + wid;
            const _Float16* src;
            int ldsoff;
            if (cid < 32) {            // A: plane p, 16-row subtile c
                int p = cid >> 3, c = cid & 7;
                src = Sp + (size_t)p * PS + (size_t)(m0 + c * 16 + fr) * DD + k0 + fq * 8;
                ldsoff = p * 8192 + c * 1024;
            } else {                   // B: Eh/El
                int r = cid - 32;
                int q = r >> 3, c = r & 7;
                const _Float16* Ep = q ? El : Eh;
                src = Ep + (size_t)(v0 + c * 16 + fr) * DD + k0 + fq * 8;
                ldsoff = 32768 + q * 8192 + c * 1024;
            }
            async16(lds + ldsoff, src);
        }
        __syncthreads();

        f16x8 aRh[4], aRl[4], aIh[4], aIl[4];
        #pragma unroll
        for (int ms = 0; ms < 4; ++ms) {
            int off = ((wm >> 4) + ms) * 1024 + lane * 16;
            aRh[ms] = *(const f16x8*)(lds + off);
            aRl[ms] = *(const f16x8*)(lds + 8192 + off);
            aIh[ms] = *(const f16x8*)(lds + 16384 + off);
            aIl[ms] = *(const f16x8*)(lds + 24576 + off);
        }
        #pragma unroll
        for (int vs = 0; vs < 4; ++vs) {
            int boff = ((wv >> 4) + vs) * 1024 + lane * 16;
            f16x8 bh = *(const f16x8*)(lds + 32768 + boff);
            f16x8 bl = *(const f16x8*)(lds + 40960 + boff);
            #pragma unroll
            for (int ms = 0; ms < 4; ++ms) {
                accR[ms][vs] = __builtin_amdgcn_mfma_f32_16x16x32_f16(aRh[ms], bh, accR[ms][vs], 0, 0, 0);
                accR[ms][vs] = __builtin_amdgcn_mfma_f32_16x16x32_f16(aRh[ms], bl, accR[ms][vs], 0, 0, 0);
                accR[ms][vs] = __builtin_amdgcn_mfma_f32_16x16x32_f16(aRl[ms], bh, accR[ms][vs], 0, 0, 0);
                accI[ms][vs] = __builtin_amdgcn_mfma_f32_16x16x32_f16(aIh[ms], bh, accI[ms][vs], 0, 0, 0);
                accI[ms][vs] = __builtin_amdgcn_mfma_f32_16x16x32_f16(aIh[ms], bl, accI[ms][vs], 0, 0, 0);
                accI[ms][vs] = __builtin_amdgcn_mfma_f32_16x16x32_f16(aIl[ms], bh, accI[ms][vs], 0, 0, 0);
            }
        }
        __syncthreads();
    }

    #pragma unroll
    for (int ms = 0; ms < 4; ++ms) {
        #pragma unroll
        for (int vs = 0; vs < 4; ++vs) {
            #pragma unroll
            for (int r = 0; r < 4; ++r) {
                int row = m0 + wm + ms * 16 + fq * 4 + r;
                int col = v0 + wv + vs * 16 + fr;
                float ar = accR[ms][vs][r], ai = accI[ms][vs][r];
                out[(size_t)row * VV + col] = logf(fmaf(ar, ar, fmaf(ai, ai, 1e-8f)));
            }
        }
    }
}

extern "C" void kernel_launch(void* const* d_in, const int* in_sizes, int n_in,
                              void* d_out, int out_size, void* d_ws, size_t ws_size,
                              hipStream_t stream) {
    const int*   tok  = (const int*)d_in[0];
    const float* er   = (const float*)d_in[1];
    const float* ei   = (const float*)d_in[2];
    const float* Win  = (const float*)d_in[3];
    const float* ck   = (const float*)d_in[4];
    const float* Alog = (const float*)d_in[5];
    const float* dts  = (const float*)d_in[6];
    const float* dtb  = (const float*)d_in[7];
    const float* WB   = (const float*)d_in[8];
    const float* WC   = (const float*)d_in[9];
    const float* Dk   = (const float*)d_in[10];
    const float* Wo   = (const float*)d_in[11];
    const float* Lop  = (const float*)d_in[12];
    const float* nw   = (const float*)d_in[13];
    float* out = (float*)d_out;

    float* W0   = (float*)d_ws;
    float* P    = W0;                 // planes 0,1: psi f32
    float* XZ   = W0 + 2 * PS;        // planes 2..5 (layer phase)
    float* X    = W0 + 6 * PS;        // planes 6,7
    float* DTp  = W0 + 8 * PS;        // plane 8
    float* ZU   = W0 + 9 * PS;        // planes 9,10
    float* Y8T  = W0 + 11 * PS;       // planes 11..18 (8 partial planes, [g][bd][s])
    _Float16* YOh = (_Float16*)(W0 + 19 * PS);
    _Float16* YOl = (_Float16*)(W0 + 20 * PS);
    _Float16* Ph  = (_Float16*)(W0 + 21 * PS);
    _Float16* Pl  = (_Float16*)(W0 + 22 * PS);
    float* BR   = XZ;                 // alias planes 2,3 (written by gemm2, after T-planes dead)
    // T-planes for scans: alias planes 2,3,4 (XZ dead after conv; BR written later)
    float* DTt  = W0 + 2 * PS;
    float* XrT  = W0 + 3 * PS;
    float* XiT  = W0 + 4 * PS;
    // small arrays: planes 23,24
    float* BC2  = W0 + 23 * PS;                    // MM*64*4 floats (2MB)
    float* DIAG = BC2 + (size_t)MM * 64 * 4;
    float* PH   = DIAG + BB * DD;
    float2* HB  = (float2*)(PH + 16);              // CH*BDW*NN float2 (4MB)
    float* SDT  = (float*)(HB + (size_t)CH * BDW * NN);
    // weight splits (transposed): planes 25..30
    _Float16* Winh = (_Float16*)(W0 + 25 * PS);
    _Float16* Winl = (_Float16*)(W0 + 27 * PS);
    _Float16* Woh  = (_Float16*)(W0 + 29 * PS);
    _Float16* Wol  = (_Float16*)(W0 + 30 * PS);
    // end phase (layer buffers dead)
    _Float16* Sp  = (_Float16*)(W0 + 2 * PS);
    _Float16* Ehp = (_Float16*)(W0 + 4 * PS);
    _Float16* Elp = (_Float16*)(W0 + 13 * PS);

    k_split_w<<<dim3(32, 64, 4), 256, 0, stream>>>(Win, Winh, Winl, 1024, 2048);
    k_split_w<<<dim3(32, 32, 4), 256, 0, stream>>>(Wo, Woh, Wol, 1024, 1024);

    k_embed<<<(int)(PS / 4 / 256), 256, 0, stream>>>(tok, er, ei, P, P + PS, Ph, Pl);

    for (int l = 0; l < LLAYERS; ++l) {
        const float* Lopl = Lop + (size_t)l * KLL * DD;
        const float* Alogl = Alog + (size_t)l * DD * NN;
        const _Float16* Wih = Winh + (size_t)l * 2048 * 1024;
        const _Float16* Wil = Winl + (size_t)l * 2048 * 1024;
        const _Float16* Wohl = Woh + (size_t)l * 1024 * 1024;
        const _Float16* Woll = Wol + (size_t)l * 1024 * 1024;

        k_gemm_f16<<<dim3(2048 / 128, M2 / 128), 256, 0, stream>>>(Ph, Pl, Wih, Wil, XZ, 2048);
        k_conv<<<(int)(MM * (size_t)DD / 4 / 256), 256, 0, stream>>>(XZ, ck + (size_t)l * DD * KCC,
                dts + l * DD, dtb + l * DD, X, X + PS, DTp, ZU, ZU + PS);
        k_bc<<<M2 / 4, 256, 0, stream>>>(X, WB + (size_t)l * NN * DD, WC + (size_t)l * NN * DD, BC2);
        k_xpose<<<dim3(DD / 64, MM / 64), 256, 0, stream>>>(DTp, X, X + PS, DTt, XrT, XiT);
        k_scan1<<<(BDW * CH) / 4, 256, 0, stream>>>(XrT, XiT, DTt, (const float4*)BC2, Alogl, Y8T, HB, SDT);
        k_scan3<<<(BDW * 3) / 4, 256, 0, stream>>>(DTt, BC2, Alogl, HB, SDT, Y8T);
        k_ymod<<<dim3(DD / 64, MM / 64), 256, 0, stream>>>(Y8T, X, ZU, ZU + PS, Dk + l * DD, YOh, YOl);
        k_gemm_n64<<<dim3(1024 / 64, M2 / 128), 256, 0, stream>>>(YOh, YOl, Wohl, Woll, BR, 1024);
        k_projcorr<<<M2 / 4, 256, 0, stream>>>(BR, Lopl);
        k_diag<<<dim3(DD / 64, BB), 256, 0, stream>>>(BR, DIAG);
        k_phase<<<BB, 256, 0, stream>>>(DIAG, PH);
        k_resid<<<(int)(PS / 4 / 256), 256, 0, stream>>>(P, P + PS, BR, PH, Ph, Pl);
    }

    k_rms<<<MM, 256, 0, stream>>>(P, P + PS, nw, Sp);
    k_split_e<<<(int)((size_t)VV * DD / 8 / 256), 256, 0, stream>>>(er, Ehp, Elp);
    k_logits_mfma<<<4000, 256, 0, stream>>>(Sp, Ehp, Elp, out);
}

// Round 13
// 3163.500 us; speedup vs baseline: 1.1186x; 1.0095x over previous
//
#include <hip/hip_runtime.h>
#include <math.h>

#define BB 2
#define SS 1024
#define DD 1024
#define NN 64
#define LLAYERS 4
#define KCC 4
#define KLL 4
#define VV 32000
#define MM (BB*SS)          // 2048
#define M2 (2*MM)           // 4096
#define PS ((size_t)MM*DD)  // 2097152 floats per plane
#define CH 2                // time chunks for scan (scan3 rework = (CH-1)/CH)
#define LC (SS/CH)          // 512 steps per chunk
#define BDW (BB*DD)         // 2048 (b,d) pairs

#define SCALE_F 0.35355339059327373f
#define GAMMA_F 0.01f
#define PHASE_COS 0.99500416527802576f
#define PHASE_SIN 0.09983341664682815f

typedef _Float16 f16x8 __attribute__((ext_vector_type(8)));
typedef _Float16 f16x4 __attribute__((ext_vector_type(4)));
typedef float f32x4 __attribute__((ext_vector_type(4)));

__device__ __forceinline__ float softplus_f(float x) {
    return fmaxf(x, 0.f) + log1pf(expf(-fabsf(x)));
}

__device__ __forceinline__ void async16(void* lds_dst, const void* g_src) {
    __builtin_amdgcn_global_load_lds(
        (const __attribute__((address_space(1))) unsigned int*)g_src,
        (__attribute__((address_space(3))) unsigned int*)lds_dst,
        16, 0, 0);
}

// 16-lane row-sum (VALU DPP row_shr tree). Partial sum valid in lane 15 mod 16.
__device__ __forceinline__ float rsum16_dpp(float v) {
    int x;
    x = __float_as_int(v);
    v += __int_as_float(__builtin_amdgcn_update_dpp(0, x, 0x111, 0xf, 0xf, true));
    x = __float_as_int(v);
    v += __int_as_float(__builtin_amdgcn_update_dpp(0, x, 0x112, 0xf, 0xf, true));
    x = __float_as_int(v);
    v += __int_as_float(__builtin_amdgcn_update_dpp(0, x, 0x114, 0xf, 0xf, true));
    x = __float_as_int(v);
    v += __int_as_float(__builtin_amdgcn_update_dpp(0, x, 0x118, 0xf, 0xf, true));
    return v;
}

// ---------------- K0: transpose + f16 hi/lo split of weights ----------------
__global__ __launch_bounds__(256) void k_split_w(const float* __restrict__ W,
        _Float16* __restrict__ Wh, _Float16* __restrict__ Wl, int Ksz, int Nsz) {
    __shared__ float t[32][33];
    int k0 = blockIdx.x * 32, n0 = blockIdx.y * 32;
    size_t base = (size_t)blockIdx.z * Ksz * Nsz;
    int r = threadIdx.x >> 3, c4 = (threadIdx.x & 7) * 4;
    float4 v = *(const float4*)(W + base + (size_t)(k0 + r) * Nsz + n0 + c4);
    t[r][c4 + 0] = v.x; t[r][c4 + 1] = v.y; t[r][c4 + 2] = v.z; t[r][c4 + 3] = v.w;
    __syncthreads();
    f16x4 hi, lo;
    #pragma unroll
    for (int j = 0; j < 4; ++j) {
        float x = t[c4 + j][r];
        _Float16 h = (_Float16)x;
        hi[j] = h; lo[j] = (_Float16)(x - (float)h);
    }
    size_t o = base + (size_t)(n0 + r) * Ksz + k0 + c4;
    *(f16x4*)(Wh + o) = hi;
    *(f16x4*)(Wl + o) = lo;
}

// ---------------- K1: embedding gather + psi f16 split ----------------
__global__ __launch_bounds__(256) void k_embed(const int* __restrict__ tok,
        const float* __restrict__ er, const float* __restrict__ ei,
        float* __restrict__ Pr, float* __restrict__ Pi,
        _Float16* __restrict__ Ph, _Float16* __restrict__ Pl) {
    int i = blockIdx.x * 256 + threadIdx.x;      // over PS/4
    int d4 = (i & (DD/4 - 1)) * 4;
    int m  = i >> 8;
    int t = tok[m];
    float4 r  = *(const float4*)(er + (size_t)t * DD + d4);
    float4 im = *(const float4*)(ei + (size_t)t * DD + d4);
    size_t o = (size_t)m * DD + d4;
    *(float4*)(Pr + o) = r;
    *(float4*)(Pi + o) = im;
    float vr[4] = {r.x, r.y, r.z, r.w}, vi[4] = {im.x, im.y, im.z, im.w};
    f16x4 rh, rl, ih, il;
    #pragma unroll
    for (int j = 0; j < 4; ++j) {
        _Float16 h = (_Float16)vr[j]; rh[j] = h; rl[j] = (_Float16)(vr[j] - (float)h);
        _Float16 g = (_Float16)vi[j]; ih[j] = g; il[j] = (_Float16)(vi[j] - (float)g);
    }
    *(f16x4*)(Ph + o) = rh;      *(f16x4*)(Pl + o) = rl;
    *(f16x4*)(Ph + PS + o) = ih; *(f16x4*)(Pl + PS + o) = il;
}

// ---------------- K2: f16-split MFMA GEMM: C(M2 x N) = A @ B^T ----------------
__global__ __launch_bounds__(256, 2) void k_gemm_f16(
        const _Float16* __restrict__ Ah, const _Float16* __restrict__ Al,
        const _Float16* __restrict__ Bh, const _Float16* __restrict__ Bl,
        float* __restrict__ C, int Nsz) {
    __shared__ __align__(16) unsigned char lds[32768];
    const int lane = threadIdx.x & 63;
    const int wid  = threadIdx.x >> 6;
    const int wm = (wid >> 1) * 64;
    const int wv = (wid & 1) * 64;
    const int n0 = blockIdx.x * 128;
    const int m0 = blockIdx.y * 128;
    const int fr = lane & 15, fq = lane >> 4;

    f32x4 acc[4][4] = {};

    for (int k0 = 0; k0 < 1024; k0 += 32) {
        #pragma unroll
        for (int j = 0; j < 8; ++j) {
            int cid = wid * 8 + j;
            int sel = cid >> 3, c = cid & 7;
            const _Float16* bp = (sel == 0) ? Ah : (sel == 1) ? Al : (sel == 2) ? Bh : Bl;
            int rbase = ((sel < 2) ? m0 : n0) + c * 16 + fr;
            async16(lds + cid * 1024, bp + (size_t)rbase * 1024 + k0 + fq * 8);
        }
        __syncthreads();

        f16x8 ah[4], al[4];
        #pragma unroll
        for (int ms = 0; ms < 4; ++ms) {
            int off = ((wm >> 4) + ms) * 1024 + lane * 16;
            ah[ms] = *(const f16x8*)(lds + off);
            al[ms] = *(const f16x8*)(lds + 8192 + off);
        }
        #pragma unroll
        for (int vs = 0; vs < 4; ++vs) {
            int boff = ((wv >> 4) + vs) * 1024 + lane * 16;
            f16x8 bh = *(const f16x8*)(lds + 16384 + boff);
            f16x8 bl = *(const f16x8*)(lds + 24576 + boff);
            #pragma unroll
            for (int ms = 0; ms < 4; ++ms) {
                acc[ms][vs] = __builtin_amdgcn_mfma_f32_16x16x32_f16(ah[ms], bh, acc[ms][vs], 0, 0, 0);
                acc[ms][vs] = __builtin_amdgcn_mfma_f32_16x16x32_f16(ah[ms], bl, acc[ms][vs], 0, 0, 0);
                acc[ms][vs] = __builtin_amdgcn_mfma_f32_16x16x32_f16(al[ms], bh, acc[ms][vs], 0, 0, 0);
            }
        }
        __syncthreads();
    }

    #pragma unroll
    for (int ms = 0; ms < 4; ++ms) {
        #pragma unroll
        for (int vs = 0; vs < 4; ++vs) {
            #pragma unroll
            for (int r = 0; r < 4; ++r) {
                int row = m0 + wm + ms * 16 + fq * 4 + r;
                int col = n0 + wv + vs * 16 + fr;
                C[(size_t)row * Nsz + col] = acc[ms][vs][r];
            }
        }
    }
}

// ---------------- K2b: 128x64-tile f16-split GEMM (N=1024 path) ----------------
__global__ __launch_bounds__(256, 2) void k_gemm_n64(
        const _Float16* __restrict__ Ah, const _Float16* __restrict__ Al,
        const _Float16* __restrict__ Bh, const _Float16* __restrict__ Bl,
        float* __restrict__ C, int Nsz) {
    __shared__ __align__(16) unsigned char lds[24576];
    const int lane = threadIdx.x & 63;
    const int wid  = threadIdx.x >> 6;
    const int wm = (wid >> 1) * 64;
    const int wv = (wid & 1) * 32;
    const int n0 = blockIdx.x * 64;
    const int m0 = blockIdx.y * 128;
    const int fr = lane & 15, fq = lane >> 4;

    f32x4 acc[4][2] = {};

    for (int k0 = 0; k0 < 1024; k0 += 32) {
        #pragma unroll
        for (int j = 0; j < 6; ++j) {
            int cid = j * 4 + wid;
            const _Float16* bp;
            int rbase, ldsoff;
            if (cid < 16) {           // A: plane cid>>3, 16-row subtile cid&7
                bp = (cid >> 3) ? Al : Ah;
                rbase = m0 + (cid & 7) * 16 + fr;
                ldsoff = cid * 1024;
            } else {                  // B: plane (cid-16)>>2, subtile (cid-16)&3
                int r = cid - 16;
                bp = (r >> 2) ? Bl : Bh;
                rbase = n0 + (r & 3) * 16 + fr;
                ldsoff = 16384 + r * 1024;
            }
            async16(lds + ldsoff, bp + (size_t)rbase * 1024 + k0 + fq * 8);
        }
        __syncthreads();

        f16x8 ah[4], al[4];
        #pragma unroll
        for (int ms = 0; ms < 4; ++ms) {
            int off = ((wm >> 4) + ms) * 1024 + lane * 16;
            ah[ms] = *(const f16x8*)(lds + off);
            al[ms] = *(const f16x8*)(lds + 8192 + off);
        }
        #pragma unroll
        for (int vs = 0; vs < 2; ++vs) {
            int boff = ((wv >> 4) + vs) * 1024 + lane * 16;
            f16x8 bh = *(const f16x8*)(lds + 16384 + boff);
            f16x8 bl = *(const f16x8*)(lds + 20480 + boff);
            #pragma unroll
            for (int ms = 0; ms < 4; ++ms) {
                acc[ms][vs] = __builtin_amdgcn_mfma_f32_16x16x32_f16(ah[ms], bh, acc[ms][vs], 0, 0, 0);
                acc[ms][vs] = __builtin_amdgcn_mfma_f32_16x16x32_f16(ah[ms], bl, acc[ms][vs], 0, 0, 0);
                acc[ms][vs] = __builtin_amdgcn_mfma_f32_16x16x32_f16(al[ms], bh, acc[ms][vs], 0, 0, 0);
            }
        }
        __syncthreads();
    }

    #pragma unroll
    for (int ms = 0; ms < 4; ++ms) {
        #pragma unroll
        for (int vs = 0; vs < 2; ++vs) {
            #pragma unroll
            for (int r = 0; r < 4; ++r) {
                int row = m0 + wm + ms * 16 + fq * 4 + r;
                int col = n0 + wv + vs * 16 + fr;
                C[(size_t)row * Nsz + col] = acc[ms][vs][r];
            }
        }
    }
}

// ---------------- K3: causal depthwise conv + csilu + dt + z-gate (x4 vec) ----------------
__global__ __launch_bounds__(256) void k_conv(const float* __restrict__ XZ,
        const float* __restrict__ ck, const float* __restrict__ dts,
        const float* __restrict__ dtb,
        float* __restrict__ Xr, float* __restrict__ Xi, float* __restrict__ DT,
        float* __restrict__ ZUr, float* __restrict__ ZUi) {
    int i4 = blockIdx.x * 256 + threadIdx.x;     // over MM*DD/4
    int dq = (i4 & (DD / 4 - 1)) * 4;
    int m  = i4 >> 8;
    int b = m >> 10, s = m & (SS - 1);
    size_t i = (size_t)m * DD + dq;
    float kw[4][4];
    #pragma unroll
    for (int c = 0; c < 4; ++c)
        *(float4*)kw[c] = *(const float4*)(ck + (size_t)(dq + c) * KCC);
    float cr[4] = {0.f, 0.f, 0.f, 0.f}, ci[4] = {0.f, 0.f, 0.f, 0.f};
    #pragma unroll
    for (int j = 0; j < KCC; ++j) {
        int sj = s - (KCC - 1) + j;
        if (sj >= 0) {
            size_t mm = ((size_t)(b << 10) + sj) * 2048 + dq;
            float4 xr4 = *(const float4*)(XZ + mm);
            float4 xi4 = *(const float4*)(XZ + (size_t)MM * 2048 + mm);
            float xr_[4] = {xr4.x, xr4.y, xr4.z, xr4.w};
            float xi_[4] = {xi4.x, xi4.y, xi4.z, xi4.w};
            #pragma unroll
            for (int c = 0; c < 4; ++c) {
                cr[c] = fmaf(xr_[c], kw[c][j], cr[c]);
                ci[c] = fmaf(xi_[c], kw[c][j], ci[c]);
            }
        }
    }
    float4 dts4 = *(const float4*)(dts + dq);
    float4 dtb4 = *(const float4*)(dtb + dq);
    float dts_[4] = {dts4.x, dts4.y, dts4.z, dts4.w};
    float dtb_[4] = {dtb4.x, dtb4.y, dtb4.z, dtb4.w};
    float xro[4], xio[4], dto[4];
    #pragma unroll
    for (int c = 0; c < 4; ++c) {
        float mag = sqrtf(cr[c] * cr[c] + ci[c] * ci[c]);
        float sg = 1.f / (1.f + expf(-mag));
        xro[c] = cr[c] * sg; xio[c] = ci[c] * sg;
        dto[c] = softplus_f(fmaf(xro[c], dts_[c], dtb_[c]));
    }
    *(float4*)(Xr + i) = make_float4(xro[0], xro[1], xro[2], xro[3]);
    *(float4*)(Xi + i) = make_float4(xio[0], xio[1], xio[2], xio[3]);
    *(float4*)(DT + i) = make_float4(dto[0], dto[1], dto[2], dto[3]);
    float4 zr4 = *(const float4*)(XZ + (size_t)m * 2048 + DD + dq);
    float4 zi4 = *(const float4*)(XZ + (size_t)(MM + m) * 2048 + DD + dq);
    float zr_[4] = {zr4.x, zr4.y, zr4.z, zr4.w};
    float zi_[4] = {zi4.x, zi4.y, zi4.z, zi4.w};
    float zur[4], zui[4];
    #pragma unroll
    for (int c = 0; c < 4; ++c) {
        float mz = sqrtf(zr_[c] * zr_[c] + zi_[c] * zi_[c]);
        float sz = 1.f / (1.f + expf(-mz));
        zur[c] = zr_[c] * sz; zui[c] = zi_[c] * sz;
    }
    *(float4*)(ZUr + i) = make_float4(zur[0], zur[1], zur[2], zur[3]);
    *(float4*)(ZUi + i) = make_float4(zui[0], zui[1], zui[2], zui[3]);
}

// ---------------- K4: Bc/Cc projections -> packed BC2[(m*64+n)*4 + {br,bi,cr,ci}] ----------------
__global__ __launch_bounds__(256) void k_bc(const float* __restrict__ X,
        const float* __restrict__ WBp, const float* __restrict__ WCp,
        float* __restrict__ BC2) {
    __shared__ float xs[4][DD];
    __shared__ float red[4 * 256];
    int r0 = blockIdx.x * 4;
    for (int f = threadIdx.x; f < 4 * (DD / 4); f += 256) {
        int r = f / (DD / 4), c = (f % (DD / 4)) * 4;
        *(float4*)(&xs[r][c]) = *(const float4*)(X + (size_t)(r0 + r) * DD + c);
    }
    __syncthreads();
    int out = threadIdx.x & 127;
    int half = threadIdx.x >> 7;
    const float* Wrow = (out < 64) ? (WBp + (size_t)out * DD) : (WCp + (size_t)(out - 64) * DD);
    float acc[4] = {0.f, 0.f, 0.f, 0.f};
    for (int k = half * 512; k < half * 512 + 512; k += 4) {
        float4 w = *(const float4*)(Wrow + k);
        #pragma unroll
        for (int r = 0; r < 4; ++r) {
            float4 x4 = *(float4*)(&xs[r][k]);
            acc[r] = fmaf(x4.x, w.x, fmaf(x4.y, w.y, fmaf(x4.z, w.z, fmaf(x4.w, w.w, acc[r]))));
        }
    }
    #pragma unroll
    for (int r = 0; r < 4; ++r) red[r * 256 + threadIdx.x] = acc[r];
    __syncthreads();
    if (threadIdx.x < 128) {
        int isIm = (r0 >= MM) ? 1 : 0;
        int n = out & 63;
        int comp = ((out >> 6) << 1) | isIm;   // br=0, bi=1, cr=2, ci=3
        #pragma unroll
        for (int r = 0; r < 4; ++r) {
            float v = red[r * 256 + threadIdx.x] + red[r * 256 + threadIdx.x + 128];
            int m = (r0 + r) & (MM - 1);
            BC2[((size_t)m * 64 + n) * 4 + comp] = v;
        }
    }
}

// ---------------- K3b: transpose DT/Xr/Xi -> [bd][s] for the scans ----------------
__global__ __launch_bounds__(256) void k_xpose(const float* __restrict__ A,
        const float* __restrict__ B, const float* __restrict__ C,
        float* __restrict__ At, float* __restrict__ Bt, float* __restrict__ Ct) {
    __shared__ float tile[64][65];
    int d0 = blockIdx.x * 64, m0 = blockIdx.y * 64;
    int b = m0 >> 10, s0 = m0 & (SS - 1);
    int tx = threadIdx.x & 63, ty = threadIdx.x >> 6;
    const float* in[3]  = {A, B, C};
    float* outp[3] = {At, Bt, Ct};
    #pragma unroll
    for (int p = 0; p < 3; ++p) {
        #pragma unroll
        for (int k = 0; k < 16; ++k) {
            int r = ty + 4 * k;
            tile[r][tx] = in[p][(size_t)(m0 + r) * DD + d0 + tx];
        }
        __syncthreads();
        #pragma unroll
        for (int k = 0; k < 16; ++k) {
            int d = ty + 4 * k;
            outp[p][(size_t)(b * DD + d0 + d) * SS + s0 + tx] = tile[tx][d];
        }
        __syncthreads();
    }
}

// ---------------- K5a: scan pass 1, 4-step unrolled, vectorized T-plane loads ----------------
// Y8T: 8 planes [g16*2 + {r,i}][bd][s]. DTt/XrT/XiT in [bd][s]: one float4
// load per array per 4 steps (wave-uniform, contiguous).
__global__ __launch_bounds__(256, 8) void k_scan1(const float* __restrict__ XrT,
        const float* __restrict__ XiT, const float* __restrict__ DTt,
        const float4* __restrict__ BC2,
        const float* __restrict__ Alog, float* __restrict__ Y8T,
        float2* __restrict__ HB, float* __restrict__ SDT) {
    int w = (blockIdx.x << 2) + (threadIdx.x >> 6);   // (bd, c)
    int lane = threadIdx.x & 63;
    int c = w & (CH - 1);
    int bd = w / CH;
    int b = bd >> 10, d = bd & (DD - 1);
    float Av = -__expf(Alog[(size_t)d * NN + lane]);
    float hr = 0.f, hi = 0.f, sdt = 0.f;
    int s0 = c * LC;
    size_t mBase = (size_t)(b << 10);
    const float4* bcp = BC2 + (mBase + s0) * 64 + lane;
    size_t ys = (size_t)bd * SS + s0;
    size_t po = (size_t)(lane >> 4) * 2 * PS;
    for (int t = 0; t < LC; t += 4) {
        float4 dt4 = *(const float4*)(DTt + ys);
        float4 xr4 = *(const float4*)(XrT + ys);
        float4 xi4 = *(const float4*)(XiT + ys);
        float dtv[4] = {dt4.x, dt4.y, dt4.z, dt4.w};
        float xrv[4] = {xr4.x, xr4.y, xr4.z, xr4.w};
        float xiv[4] = {xi4.x, xi4.y, xi4.z, xi4.w};
        float4 yrq, yiq;
        #pragma unroll
        for (int k = 0; k < 4; ++k) {
            float4 bc = bcp[(size_t)k * 64];
            float g = __expf(dtv[k] * Av);
            float dxr = dtv[k] * xrv[k], dxi = dtv[k] * xiv[k];
            hr = fmaf(g, hr, fmaf(dxr, bc.x, -dxi * bc.y));
            hi = fmaf(g, hi, fmaf(dxr, bc.y,  dxi * bc.x));
            sdt += dtv[k];
            float pr = rsum16_dpp(hr * bc.z - hi * bc.w);
            float pi = rsum16_dpp(hr * bc.w + hi * bc.z);
            if (k == 0)      { yrq.x = pr; yiq.x = pi; }
            else if (k == 1) { yrq.y = pr; yiq.y = pi; }
            else if (k == 2) { yrq.z = pr; yiq.z = pi; }
            else             { yrq.w = pr; yiq.w = pi; }
        }
        bcp += 256;
        if ((lane & 15) == 15) {
            *(float4*)(Y8T + po + ys)      = yrq;
            *(float4*)(Y8T + po + PS + ys) = yiq;
        }
        ys += 4;
    }
    HB[((size_t)c * BDW + bd) * NN + lane] = make_float2(hr, hi);
    if (lane == 0) SDT[c * BDW + bd] = sdt;
}

// ---------------- K5c: inflow correction, 4-step unrolled, vectorized DT load ----------------
__global__ __launch_bounds__(256, 8) void k_scan3(const float* __restrict__ DTt,
        const float* __restrict__ BC2, const float* __restrict__ Alog,
        const float2* __restrict__ HB, const float* __restrict__ SDT,
        float* __restrict__ Y8T) {
    int w = (blockIdx.x << 2) + (threadIdx.x >> 6);   // [0, (CH-1)*BDW)
    int lane = threadIdx.x & 63;
    int cm1 = w / BDW;           // 0..CH-2 -> chunk c = cm1+1
    int bd = w % BDW;
    int b = bd >> 10, d = bd & (DD - 1);
    float Av = -__expf(Alog[(size_t)d * NN + lane]);
    float2 h0 = HB[(size_t)bd * NN + lane];
    float hr = h0.x, hi = h0.y;
    if (cm1 >= 1) {
        float2 h1 = HB[((size_t)1 * BDW + bd) * NN + lane];
        float P1 = __expf(Av * SDT[1 * BDW + bd]);
        hr = fmaf(P1, hr, h1.x); hi = fmaf(P1, hi, h1.y);
        if (cm1 >= 2) {
            float2 h2 = HB[((size_t)2 * BDW + bd) * NN + lane];
            float P2 = __expf(Av * SDT[2 * BDW + bd]);
            hr = fmaf(P2, hr, h2.x); hi = fmaf(P2, hi, h2.y);
        }
    }
    int s0 = (cm1 + 1) * LC;
    size_t mBase = (size_t)(b << 10);
    const float* ccp = BC2 + ((mBase + s0) * 64 + lane) * 4 + 2;
    size_t ys = (size_t)bd * SS + s0;
    size_t po = (size_t)(lane >> 4) * 2 * PS;
    for (int t = 0; t < LC; t += 4) {
        float4 dt4 = *(const float4*)(DTt + ys);
        float dtv[4] = {dt4.x, dt4.y, dt4.z, dt4.w};
        float4 yrq, yiq;
        #pragma unroll
        for (int k = 0; k < 4; ++k) {
            float2 cc = *(const float2*)(ccp + (size_t)k * 256);
            float g = __expf(dtv[k] * Av);
            hr *= g; hi *= g;
            float pr = rsum16_dpp(hr * cc.x - hi * cc.y);
            float pi = rsum16_dpp(hr * cc.y + hi * cc.x);
            if (k == 0)      { yrq.x = pr; yiq.x = pi; }
            else if (k == 1) { yrq.y = pr; yiq.y = pi; }
            else if (k == 2) { yrq.z = pr; yiq.z = pi; }
            else             { yrq.w = pr; yiq.w = pi; }
        }
        ccp += 1024;
        if ((lane & 15) == 15) {
            float4 orq = *(float4*)(Y8T + po + ys);
            float4 oiq = *(float4*)(Y8T + po + PS + ys);
            orq.x += yrq.x; orq.y += yrq.y; orq.z += yrq.z; orq.w += yrq.w;
            oiq.x += yiq.x; oiq.y += yiq.y; oiq.z += yiq.z; oiq.w += yiq.w;
            *(float4*)(Y8T + po + ys)      = orq;
            *(float4*)(Y8T + po + PS + ys) = oiq;
        }
        ys += 4;
    }
}

// ---------------- K6: y = (sum Y8T partials + Dk*x1) * csilu(z) -> f16 hi/lo ----------------
__global__ __launch_bounds__(256) void k_ymod(const float* __restrict__ Y8T,
        const float* __restrict__ X, const float* __restrict__ ZUr,
        const float* __restrict__ ZUi, const float* __restrict__ Dk,
        _Float16* __restrict__ YOh, _Float16* __restrict__ YOl) {
    __shared__ float tr[64][65];
    __shared__ float ti[64][65];
    int d0 = blockIdx.x * 64, m0 = blockIdx.y * 64;
    int b = m0 >> 10, s0 = m0 & (SS - 1);
    int t = threadIdx.x;
    int rr = t >> 2, c0 = (t & 3) * 4;
    size_t ybase = (size_t)(b * DD + d0 + rr) * SS + s0;
    #pragma unroll
    for (int j = 0; j < 4; ++j) {
        size_t o = ybase + c0 + j * 16;
        float4 r0 = *(const float4*)(Y8T + o);
        float4 r1 = *(const float4*)(Y8T + 2 * PS + o);
        float4 r2 = *(const float4*)(Y8T + 4 * PS + o);
        float4 r3 = *(const float4*)(Y8T + 6 * PS + o);
        float4 i0 = *(const float4*)(Y8T + PS + o);
        float4 i1 = *(const float4*)(Y8T + 3 * PS + o);
        float4 i2 = *(const float4*)(Y8T + 5 * PS + o);
        float4 i3 = *(const float4*)(Y8T + 7 * PS + o);
        float4 vr, vi;
        vr.x = (r3.x + r2.x) + (r1.x + r0.x);
        vr.y = (r3.y + r2.y) + (r1.y + r0.y);
        vr.z = (r3.z + r2.z) + (r1.z + r0.z);
        vr.w = (r3.w + r2.w) + (r1.w + r0.w);
        vi.x = (i3.x + i2.x) + (i1.x + i0.x);
        vi.y = (i3.y + i2.y) + (i1.y + i0.y);
        vi.z = (i3.z + i2.z) + (i1.z + i0.z);
        vi.w = (i3.w + i2.w) + (i1.w + i0.w);
        int sl = c0 + j * 16;
        tr[sl + 0][rr] = vr.x; tr[sl + 1][rr] = vr.y; tr[sl + 2][rr] = vr.z; tr[sl + 3][rr] = vr.w;
        ti[sl + 0][rr] = vi.x; ti[sl + 1][rr] = vi.y; ti[sl + 2][rr] = vi.z; ti[sl + 3][rr] = vi.w;
    }
    __syncthreads();
    int td = t & 63, tq = t >> 6;
    float dk = Dk[d0 + td];
    #pragma unroll
    for (int k = 0; k < 16; ++k) {
        int tm = tq * 16 + k;
        size_t i = (size_t)(m0 + tm) * DD + d0 + td;
        float yr = tr[tm][td];
        float yi = ti[tm][td];
        yr = fmaf(dk, X[i], yr);
        yi = fmaf(dk, X[PS + i], yi);
        float zr = ZUr[i], zi = ZUi[i];
        float or_ = yr * zr - yi * zi;
        float oi_ = yr * zi + yi * zr;
        _Float16 h0 = (_Float16)or_, h1 = (_Float16)oi_;
        YOh[i] = h0;      YOl[i] = (_Float16)(or_ - (float)h0);
        YOh[PS + i] = h1; YOl[PS + i] = (_Float16)(oi_ - (float)h1);
    }
}

// ---------------- K8: fused proj + correct (wave per row) ----------------
__global__ __launch_bounds__(256) void k_projcorr(float* __restrict__ BR,
        const float* __restrict__ Lop) {
    int row = (blockIdx.x << 2) + (threadIdx.x >> 6);
    int lane = threadIdx.x & 63;
    float* br = BR + (size_t)row * DD;
    float4 v[4], lw[4][4];
    float acc[4] = {0.f, 0.f, 0.f, 0.f};
    #pragma unroll
    for (int j = 0; j < 4; ++j) {
        int col = lane * 4 + j * 256;
        v[j] = *(const float4*)(br + col);
        #pragma unroll
        for (int k = 0; k < 4; ++k) {
            lw[j][k] = *(const float4*)(Lop + (size_t)k * DD + col);
            acc[k] += v[j].x * lw[j][k].x + v[j].y * lw[j][k].y
                    + v[j].z * lw[j][k].z + v[j].w * lw[j][k].w;
        }
    }
    #pragma unroll
    for (int off = 1; off <= 32; off <<= 1) {
        #pragma unroll
        for (int k = 0; k < 4; ++k) acc[k] += __shfl_xor(acc[k], off, 64);
    }
    #pragma unroll
    for (int j = 0; j < 4; ++j) {
        int col = lane * 4 + j * 256;
        float4 o;
        o.x = v[j].x - GAMMA_F * (acc[0]*lw[j][0].x + acc[1]*lw[j][1].x + acc[2]*lw[j][2].x + acc[3]*lw[j][3].x);
        o.y = v[j].y - GAMMA_F * (acc[0]*lw[j][0].y + acc[1]*lw[j][1].y + acc[2]*lw[j][2].y + acc[3]*lw[j][3].y);
        o.z = v[j].z - GAMMA_F * (acc[0]*lw[j][0].z + acc[1]*lw[j][1].z + acc[2]*lw[j][2].z + acc[3]*lw[j][3].z);
        o.w = v[j].w - GAMMA_F * (acc[0]*lw[j][0].w + acc[1]*lw[j][1].w + acc[2]*lw[j][2].w + acc[3]*lw[j][3].w);
        *(float4*)(br + col) = o;
    }
}

// ---------------- K9b: diag ----------------
__global__ __launch_bounds__(256) void k_diag(const float* __restrict__ BR,
        float* __restrict__ DG_) {
    __shared__ float red[4][64];
    int b = blockIdx.y, d0 = blockIdx.x * 64;
    int sg = threadIdx.x >> 6, ld = threadIdx.x & 63;
    float acc = 0.f;
    for (int s = sg; s < SS; s += 4) {
        size_t m = (size_t)(b * SS + s) * DD + d0 + ld;
        float r = BR[m], ii = BR[PS + m];
        acc = fmaf(r, r, fmaf(ii, ii, acc));
    }
    red[sg][ld] = acc;
    __syncthreads();
    if (threadIdx.x < 64) {
        float v = red[0][threadIdx.x] + red[1][threadIdx.x] + red[2][threadIdx.x] + red[3][threadIdx.x];
        DG_[b * DD + d0 + threadIdx.x] = v * (1.f / SS);
    }
}

// ---------------- K10: phase ----------------
__global__ __launch_bounds__(256) void k_phase(const float* __restrict__ DG_,
        float* __restrict__ PH) {
    __shared__ float mx[256], mn[256];
    int b = blockIdx.x;
    float vmax = -1e30f, vmin = 1e30f;
    for (int d = threadIdx.x; d < DD; d += 256) {
        float v = DG_[b * DD + d];
        vmax = fmaxf(vmax, v); vmin = fminf(vmin, v);
    }
    mx[threadIdx.x] = vmax; mn[threadIdx.x] = vmin;
    __syncthreads();
    for (int st = 128; st >= 1; st >>= 1) {
        if (threadIdx.x < st) {
            mx[threadIdx.x] = fmaxf(mx[threadIdx.x], mx[threadIdx.x + st]);
            mn[threadIdx.x] = fminf(mn[threadIdx.x], mn[threadIdx.x + st]);
        }
        __syncthreads();
    }
    if (threadIdx.x == 0) {
        float cond = mx[0] / (mn[0] + 1e-8f);
        bool ap = cond > 100.0f;
        PH[b * 2 + 0] = ap ? PHASE_COS : 1.f;
        PH[b * 2 + 1] = ap ? PHASE_SIN : 0.f;
    }
}

// ---------------- K11: residual + psi f16 split (x4 vec) ----------------
__global__ __launch_bounds__(256) void k_resid(float* __restrict__ Pr,
        float* __restrict__ Pi, const float* __restrict__ BR,
        const float* __restrict__ PH,
        _Float16* __restrict__ Ph, _Float16* __restrict__ Pl) {
    size_t i = ((size_t)blockIdx.x * 256 + threadIdx.x) * 4;
    int b = (int)(i >> 20);
    float pr = PH[b * 2], pih = PH[b * 2 + 1];
    float4 brr4 = *(const float4*)(BR + i);
    float4 bri4 = *(const float4*)(BR + PS + i);
    float4 pr4  = *(const float4*)(Pr + i);
    float4 pi4  = *(const float4*)(Pi + i);
    float brr[4] = {brr4.x, brr4.y, brr4.z, brr4.w};
    float bri[4] = {bri4.x, bri4.y, bri4.z, bri4.w};
    float pro[4] = {pr4.x, pr4.y, pr4.z, pr4.w};
    float pio[4] = {pi4.x, pi4.y, pi4.z, pi4.w};
    f16x4 rh, rl, ih, il;
    float nr[4], ni[4];
    #pragma unroll
    for (int c = 0; c < 4; ++c) {
        nr[c] = fmaf(SCALE_F, brr[c] * pr - bri[c] * pih, pro[c]);
        ni[c] = fmaf(SCALE_F, brr[c] * pih + bri[c] * pr, pio[c]);
        _Float16 h0 = (_Float16)nr[c]; rh[c] = h0; rl[c] = (_Float16)(nr[c] - (float)h0);
        _Float16 h1 = (_Float16)ni[c]; ih[c] = h1; il[c] = (_Float16)(ni[c] - (float)h1);
    }
    *(float4*)(Pr + i) = make_float4(nr[0], nr[1], nr[2], nr[3]);
    *(float4*)(Pi + i) = make_float4(ni[0], ni[1], ni[2], ni[3]);
    *(f16x4*)(Ph + i) = rh;      *(f16x4*)(Pl + i) = rl;
    *(f16x4*)(Ph + PS + i) = ih; *(f16x4*)(Pl + PS + i) = il;
}

// ---------------- K12: RMS norm -> f16 hi/lo split planes ----------------
__global__ __launch_bounds__(256) void k_rms(const float* __restrict__ Pr,
        const float* __restrict__ Pi, const float* __restrict__ nw,
        _Float16* __restrict__ Sp) {   // Sp: Rh | Rl | Ih | Il
    __shared__ float red[256];
    int m = blockIdx.x;
    int d = threadIdx.x * 4;
    float4 r  = *(const float4*)(Pr + (size_t)m * DD + d);
    float4 ii = *(const float4*)(Pi + (size_t)m * DD + d);
    float acc = r.x*r.x + r.y*r.y + r.z*r.z + r.w*r.w
              + ii.x*ii.x + ii.y*ii.y + ii.z*ii.z + ii.w*ii.w;
    red[threadIdx.x] = acc;
    __syncthreads();
    for (int st = 128; st >= 1; st >>= 1) {
        if (threadIdx.x < st) red[threadIdx.x] += red[threadIdx.x + st];
        __syncthreads();
    }
    float inv = 1.f / sqrtf(red[0] * (1.f / DD) + 1e-8f);
    float4 w = *(const float4*)(nw + d);
    float qr[4] = {r.x*inv*w.x, r.y*inv*w.y, r.z*inv*w.z, r.w*inv*w.w};
    float qi[4] = {ii.x*inv*w.x, ii.y*inv*w.y, ii.z*inv*w.z, ii.w*inv*w.w};
    f16x4 rh, rl, ih, il;
    #pragma unroll
    for (int j = 0; j < 4; ++j) {
        _Float16 h = (_Float16)qr[j]; rh[j] = h; rl[j] = (_Float16)(qr[j] - (float)h);
        _Float16 g = (_Float16)qi[j]; ih[j] = g; il[j] = (_Float16)(qi[j] - (float)g);
    }
    size_t o = (size_t)m * DD + d;
    *(f16x4*)(Sp + o)          = rh;
    *(f16x4*)(Sp + PS + o)     = rl;
    *(f16x4*)(Sp + 2 * PS + o) = ih;
    *(f16x4*)(Sp + 3 * PS + o) = il;
}

// ---------------- K12b: split emb_r f32 -> f16 hi/lo ----------------
__global__ __launch_bounds__(256) void k_split_e(const float* __restrict__ E,
        _Float16* __restrict__ Eh, _Float16* __restrict__ El) {
    size_t i = (size_t)(blockIdx.x * 256 + threadIdx.x) * 8;
    float4 a = *(const float4*)(E + i);
    float4 b = *(const float4*)(E + i + 4);
    float v[8] = {a.x, a.y, a.z, a.w, b.x, b.y, b.z, b.w};
    f16x8 hi, lo;
    #pragma unroll
    for (int j = 0; j < 8; ++j) {
        _Float16 h = (_Float16)v[j];
        hi[j] = h; lo[j] = (_Float16)(v[j] - (float)h);
    }
    *(f16x8*)(Eh + i) = hi;
    *(f16x8*)(El + i) = lo;
}

// ---------------- K13: MFMA f16-split logits GEMM (round-9 form, best known) ----------------
// XCD-pinned mapping: XCD x owns m-tiles {2x, 2x+1} (A = 2MB, L2-resident);
// all XCDs sweep v in lockstep so each E-tile is L3-fetched once, read 16x.
__global__ __launch_bounds__(256, 2) void k_logits_mfma(
        const _Float16* __restrict__ Sp,   // Rh|Rl|Ih|Il planes
        const _Float16* __restrict__ Eh, const _Float16* __restrict__ El,
        float* __restrict__ out) {
    __shared__ __align__(16) unsigned char lds[49152];
    const int lane = threadIdx.x & 63;
    const int wid  = threadIdx.x >> 6;
    const int wm = (wid >> 1) * 64;
    const int wv = (wid & 1) * 64;
    const int fr = lane & 15, fq = lane >> 4;
    int x = blockIdx.x & 7;
    int j = blockIdx.x >> 3;
    const int m0 = ((x << 1) | (j & 1)) << 7;
    const int v0 = (j >> 1) << 7;

    f32x4 accR[4][4] = {};
    f32x4 accI[4][4] = {};

    for (int k0 = 0; k0 < DD; k0 += 32) {
        #pragma unroll
        for (int jj = 0; jj < 12; ++jj) {
            int cid = jj * 4 + wid;
            const _Float16* src;
            int ldsoff;
            if (cid < 32) {            // A: plane p, 16-row subtile c
                int p = cid >> 3, c = cid & 7;
                src = Sp + (size_t)p * PS + (size_t)(m0 + c * 16 + fr) * DD + k0 + fq * 8;
                ldsoff = p * 8192 + c * 1024;
            } else {                   // B: Eh/El
                int r = cid - 32;
                int q = r >> 3, c = r & 7;
                const _Float16* Ep = q ? El : Eh;
                src = Ep + (size_t)(v0 + c * 16 + fr) * DD + k0 + fq * 8;
                ldsoff = 32768 + q * 8192 + c * 1024;
            }
            async16(lds + ldsoff, src);
        }
        __syncthreads();

        f16x8 aRh[4], aRl[4], aIh[4], aIl[4];
        #pragma unroll
        for (int ms = 0; ms < 4; ++ms) {
            int off = ((wm >> 4) + ms) * 1024 + lane * 16;
            aRh[ms] = *(const f16x8*)(lds + off);
            aRl[ms] = *(const f16x8*)(lds + 8192 + off);
            aIh[ms] = *(const f16x8*)(lds + 16384 + off);
            aIl[ms] = *(const f16x8*)(lds + 24576 + off);
        }
        #pragma unroll
        for (int vs = 0; vs < 4; ++vs) {
            int boff = ((wv >> 4) + vs) * 1024 + lane * 16;
            f16x8 bh = *(const f16x8*)(lds + 32768 + boff);
            f16x8 bl = *(const f16x8*)(lds + 40960 + boff);
            #pragma unroll
            for (int ms = 0; ms < 4; ++ms) {
                accR[ms][vs] = __builtin_amdgcn_mfma_f32_16x16x32_f16(aRh[ms], bh, accR[ms][vs], 0, 0, 0);
                accR[ms][vs] = __builtin_amdgcn_mfma_f32_16x16x32_f16(aRh[ms], bl, accR[ms][vs], 0, 0, 0);
                accR[ms][vs] = __builtin_amdgcn_mfma_f32_16x16x32_f16(aRl[ms], bh, accR[ms][vs], 0, 0, 0);
                accI[ms][vs] = __builtin_amdgcn_mfma_f32_16x16x32_f16(aIh[ms], bh, accI[ms][vs], 0, 0, 0);
                accI[ms][vs] = __builtin_amdgcn_mfma_f32_16x16x32_f16(aIh[ms], bl, accI[ms][vs], 0, 0, 0);
                accI[ms][vs] = __builtin_amdgcn_mfma_f32_16x16x32_f16(aIl[ms], bh, accI[ms][vs], 0, 0, 0);
            }
        }
        __syncthreads();
    }

    #pragma unroll
    for (int ms = 0; ms < 4; ++ms) {
        #pragma unroll
        for (int vs = 0; vs < 4; ++vs) {
            #pragma unroll
            for (int r = 0; r < 4; ++r) {
                int row = m0 + wm + ms * 16 + fq * 4 + r;
                int col = v0 + wv + vs * 16 + fr;
                float ar = accR[ms][vs][r], ai = accI[ms][vs][r];
                out[(size_t)row * VV + col] = logf(fmaf(ar, ar, fmaf(ai, ai, 1e-8f)));
            }
        }
    }
}

extern "C" void kernel_launch(void* const* d_in, const int* in_sizes, int n_in,
                              void* d_out, int out_size, void* d_ws, size_t ws_size,
                              hipStream_t stream) {
    const int*   tok  = (const int*)d_in[0];
    const float* er   = (const float*)d_in[1];
    const float* ei   = (const float*)d_in[2];
    const float* Win  = (const float*)d_in[3];
    const float* ck   = (const float*)d_in[4];
    const float* Alog = (const float*)d_in[5];
    const float* dts  = (const float*)d_in[6];
    const float* dtb  = (const float*)d_in[7];
    const float* WB   = (const float*)d_in[8];
    const float* WC   = (const float*)d_in[9];
    const float* Dk   = (const float*)d_in[10];
    const float* Wo   = (const float*)d_in[11];
    const float* Lop  = (const float*)d_in[12];
    const float* nw   = (const float*)d_in[13];
    float* out = (float*)d_out;

    float* W0   = (float*)d_ws;
    float* P    = W0;                 // planes 0,1: psi f32
    float* XZ   = W0 + 2 * PS;        // planes 2..5 (layer phase)
    float* X    = W0 + 6 * PS;        // planes 6,7
    float* DTp  = W0 + 8 * PS;        // plane 8
    float* ZU   = W0 + 9 * PS;        // planes 9,10
    float* Y8T  = W0 + 11 * PS;       // planes 11..18 (8 partial planes, [g][bd][s])
    _Float16* YOh = (_Float16*)(W0 + 19 * PS);
    _Float16* YOl = (_Float16*)(W0 + 20 * PS);
    _Float16* Ph  = (_Float16*)(W0 + 21 * PS);
    _Float16* Pl  = (_Float16*)(W0 + 22 * PS);
    float* BR   = XZ;                 // alias planes 2,3 (written by gemm2, after T-planes dead)
    // T-planes for scans: alias planes 2,3,4 (XZ dead after conv; BR written later)
    float* DTt  = W0 + 2 * PS;
    float* XrT  = W0 + 3 * PS;
    float* XiT  = W0 + 4 * PS;
    // small arrays: planes 23,24
    float* BC2  = W0 + 23 * PS;                    // MM*64*4 floats (2MB)
    float* DIAG = BC2 + (size_t)MM * 64 * 4;
    float* PH   = DIAG + BB * DD;
    float2* HB  = (float2*)(PH + 16);              // CH*BDW*NN float2
    float* SDT  = (float*)(HB + (size_t)CH * BDW * NN);
    // weight splits (transposed): planes 25..30
    _Float16* Winh = (_Float16*)(W0 + 25 * PS);
    _Float16* Winl = (_Float16*)(W0 + 27 * PS);
    _Float16* Woh  = (_Float16*)(W0 + 29 * PS);
    _Float16* Wol  = (_Float16*)(W0 + 30 * PS);
    // end phase (layer buffers dead)
    _Float16* Sp  = (_Float16*)(W0 + 2 * PS);
    _Float16* Ehp = (_Float16*)(W0 + 4 * PS);
    _Float16* Elp = (_Float16*)(W0 + 13 * PS);

    k_split_w<<<dim3(32, 64, 4), 256, 0, stream>>>(Win, Winh, Winl, 1024, 2048);
    k_split_w<<<dim3(32, 32, 4), 256, 0, stream>>>(Wo, Woh, Wol, 1024, 1024);

    k_embed<<<(int)(PS / 4 / 256), 256, 0, stream>>>(tok, er, ei, P, P + PS, Ph, Pl);

    for (int l = 0; l < LLAYERS; ++l) {
        const float* Lopl = Lop + (size_t)l * KLL * DD;
        const float* Alogl = Alog + (size_t)l * DD * NN;
        const _Float16* Wih = Winh + (size_t)l * 2048 * 1024;
        const _Float16* Wil = Winl + (size_t)l * 2048 * 1024;
        const _Float16* Wohl = Woh + (size_t)l * 1024 * 1024;
        const _Float16* Woll = Wol + (size_t)l * 1024 * 1024;

        k_gemm_f16<<<dim3(2048 / 128, M2 / 128), 256, 0, stream>>>(Ph, Pl, Wih, Wil, XZ, 2048);
        k_conv<<<(int)(MM * (size_t)DD / 4 / 256), 256, 0, stream>>>(XZ, ck + (size_t)l * DD * KCC,
                dts + l * DD, dtb + l * DD, X, X + PS, DTp, ZU, ZU + PS);
        k_bc<<<M2 / 4, 256, 0, stream>>>(X, WB + (size_t)l * NN * DD, WC + (size_t)l * NN * DD, BC2);
        k_xpose<<<dim3(DD / 64, MM / 64), 256, 0, stream>>>(DTp, X, X + PS, DTt, XrT, XiT);
        k_scan1<<<(BDW * CH) / 4, 256, 0, stream>>>(XrT, XiT, DTt, (const float4*)BC2, Alogl, Y8T, HB, SDT);
        k_scan3<<<(BDW * (CH - 1)) / 4, 256, 0, stream>>>(DTt, BC2, Alogl, HB, SDT, Y8T);
        k_ymod<<<dim3(DD / 64, MM / 64), 256, 0, stream>>>(Y8T, X, ZU, ZU + PS, Dk + l * DD, YOh, YOl);
        k_gemm_n64<<<dim3(1024 / 64, M2 / 128), 256, 0, stream>>>(YOh, YOl, Wohl, Woll, BR, 1024);
        k_projcorr<<<M2 / 4, 256, 0, stream>>>(BR, Lopl);
        k_diag<<<dim3(DD / 64, BB), 256, 0, stream>>>(BR, DIAG);
        k_phase<<<BB, 256, 0, stream>>>(DIAG, PH);
        k_resid<<<(int)(PS / 4 / 256), 256, 0, stream>>>(P, P + PS, BR, PH, Ph, Pl);
    }

    k_rms<<<MM, 256, 0, stream>>>(P, P + PS, nw, Sp);
    k_split_e<<<(int)((size_t)VV * DD / 8 / 256), 256, 0, stream>>>(er, Ehp, Elp);
    k_logits_mfma<<<4000, 256, 0, stream>>>(Sp, Ehp, Elp, out);
}

// Round 14
// 3137.508 us; speedup vs baseline: 1.1279x; 1.0083x over previous
//
#include <hip/hip_runtime.h>
#include <math.h>

#define BB 2
#define SS 1024
#define DD 1024
#define NN 64
#define LLAYERS 4
#define KCC 4
#define KLL 4
#define VV 32000
#define MM (BB*SS)          // 2048
#define M2 (2*MM)           // 4096
#define PS ((size_t)MM*DD)  // 2097152 floats per plane
#define CH 2                // time chunks for scan (scan3 rework = (CH-1)/CH)
#define LC (SS/CH)          // 512 steps per chunk
#define BDW (BB*DD)         // 2048 (b,d) pairs

#define SCALE_F 0.35355339059327373f
#define GAMMA_F 0.01f
#define PHASE_COS 0.99500416527802576f
#define PHASE_SIN 0.09983341664682815f

typedef _Float16 f16x8 __attribute__((ext_vector_type(8)));
typedef _Float16 f16x4 __attribute__((ext_vector_type(4)));
typedef float f32x4 __attribute__((ext_vector_type(4)));

__device__ __forceinline__ float softplus_f(float x) {
    return fmaxf(x, 0.f) + log1pf(expf(-fabsf(x)));
}

__device__ __forceinline__ void async16(void* lds_dst, const void* g_src) {
    __builtin_amdgcn_global_load_lds(
        (const __attribute__((address_space(1))) unsigned int*)g_src,
        (__attribute__((address_space(3))) unsigned int*)lds_dst,
        16, 0, 0);
}

// 16-lane row-sum (VALU DPP row_shr tree). Partial sum valid in lane 15 mod 16.
__device__ __forceinline__ float rsum16_dpp(float v) {
    int x;
    x = __float_as_int(v);
    v += __int_as_float(__builtin_amdgcn_update_dpp(0, x, 0x111, 0xf, 0xf, true));
    x = __float_as_int(v);
    v += __int_as_float(__builtin_amdgcn_update_dpp(0, x, 0x112, 0xf, 0xf, true));
    x = __float_as_int(v);
    v += __int_as_float(__builtin_amdgcn_update_dpp(0, x, 0x114, 0xf, 0xf, true));
    x = __float_as_int(v);
    v += __int_as_float(__builtin_amdgcn_update_dpp(0, x, 0x118, 0xf, 0xf, true));
    return v;
}

// ---------------- K0: transpose + f16 hi/lo split of weights ----------------
__global__ __launch_bounds__(256) void k_split_w(const float* __restrict__ W,
        _Float16* __restrict__ Wh, _Float16* __restrict__ Wl, int Ksz, int Nsz) {
    __shared__ float t[32][33];
    int k0 = blockIdx.x * 32, n0 = blockIdx.y * 32;
    size_t base = (size_t)blockIdx.z * Ksz * Nsz;
    int r = threadIdx.x >> 3, c4 = (threadIdx.x & 7) * 4;
    float4 v = *(const float4*)(W + base + (size_t)(k0 + r) * Nsz + n0 + c4);
    t[r][c4 + 0] = v.x; t[r][c4 + 1] = v.y; t[r][c4 + 2] = v.z; t[r][c4 + 3] = v.w;
    __syncthreads();
    f16x4 hi, lo;
    #pragma unroll
    for (int j = 0; j < 4; ++j) {
        float x = t[c4 + j][r];
        _Float16 h = (_Float16)x;
        hi[j] = h; lo[j] = (_Float16)(x - (float)h);
    }
    size_t o = base + (size_t)(n0 + r) * Ksz + k0 + c4;
    *(f16x4*)(Wh + o) = hi;
    *(f16x4*)(Wl + o) = lo;
}

// ---------------- K1: embedding gather + psi f16 split ----------------
__global__ __launch_bounds__(256) void k_embed(const int* __restrict__ tok,
        const float* __restrict__ er, const float* __restrict__ ei,
        float* __restrict__ Pr, float* __restrict__ Pi,
        _Float16* __restrict__ Ph, _Float16* __restrict__ Pl) {
    int i = blockIdx.x * 256 + threadIdx.x;      // over PS/4
    int d4 = (i & (DD/4 - 1)) * 4;
    int m  = i >> 8;
    int t = tok[m];
    float4 r  = *(const float4*)(er + (size_t)t * DD + d4);
    float4 im = *(const float4*)(ei + (size_t)t * DD + d4);
    size_t o = (size_t)m * DD + d4;
    *(float4*)(Pr + o) = r;
    *(float4*)(Pi + o) = im;
    float vr[4] = {r.x, r.y, r.z, r.w}, vi[4] = {im.x, im.y, im.z, im.w};
    f16x4 rh, rl, ih, il;
    #pragma unroll
    for (int j = 0; j < 4; ++j) {
        _Float16 h = (_Float16)vr[j]; rh[j] = h; rl[j] = (_Float16)(vr[j] - (float)h);
        _Float16 g = (_Float16)vi[j]; ih[j] = g; il[j] = (_Float16)(vi[j] - (float)g);
    }
    *(f16x4*)(Ph + o) = rh;      *(f16x4*)(Pl + o) = rl;
    *(f16x4*)(Ph + PS + o) = ih; *(f16x4*)(Pl + PS + o) = il;
}

// ---------------- K2: f16-split MFMA GEMM: C(M2 x N) = A @ B^T ----------------
__global__ __launch_bounds__(256, 2) void k_gemm_f16(
        const _Float16* __restrict__ Ah, const _Float16* __restrict__ Al,
        const _Float16* __restrict__ Bh, const _Float16* __restrict__ Bl,
        float* __restrict__ C, int Nsz) {
    __shared__ __align__(16) unsigned char lds[32768];
    const int lane = threadIdx.x & 63;
    const int wid  = threadIdx.x >> 6;
    const int wm = (wid >> 1) * 64;
    const int wv = (wid & 1) * 64;
    const int n0 = blockIdx.x * 128;
    const int m0 = blockIdx.y * 128;
    const int fr = lane & 15, fq = lane >> 4;

    f32x4 acc[4][4] = {};

    for (int k0 = 0; k0 < 1024; k0 += 32) {
        #pragma unroll
        for (int j = 0; j < 8; ++j) {
            int cid = wid * 8 + j;
            int sel = cid >> 3, c = cid & 7;
            const _Float16* bp = (sel == 0) ? Ah : (sel == 1) ? Al : (sel == 2) ? Bh : Bl;
            int rbase = ((sel < 2) ? m0 : n0) + c * 16 + fr;
            async16(lds + cid * 1024, bp + (size_t)rbase * 1024 + k0 + fq * 8);
        }
        __syncthreads();

        f16x8 ah[4], al[4];
        #pragma unroll
        for (int ms = 0; ms < 4; ++ms) {
            int off = ((wm >> 4) + ms) * 1024 + lane * 16;
            ah[ms] = *(const f16x8*)(lds + off);
            al[ms] = *(const f16x8*)(lds + 8192 + off);
        }
        #pragma unroll
        for (int vs = 0; vs < 4; ++vs) {
            int boff = ((wv >> 4) + vs) * 1024 + lane * 16;
            f16x8 bh = *(const f16x8*)(lds + 16384 + boff);
            f16x8 bl = *(const f16x8*)(lds + 24576 + boff);
            #pragma unroll
            for (int ms = 0; ms < 4; ++ms) {
                acc[ms][vs] = __builtin_amdgcn_mfma_f32_16x16x32_f16(ah[ms], bh, acc[ms][vs], 0, 0, 0);
                acc[ms][vs] = __builtin_amdgcn_mfma_f32_16x16x32_f16(ah[ms], bl, acc[ms][vs], 0, 0, 0);
                acc[ms][vs] = __builtin_amdgcn_mfma_f32_16x16x32_f16(al[ms], bh, acc[ms][vs], 0, 0, 0);
            }
        }
        __syncthreads();
    }

    #pragma unroll
    for (int ms = 0; ms < 4; ++ms) {
        #pragma unroll
        for (int vs = 0; vs < 4; ++vs) {
            #pragma unroll
            for (int r = 0; r < 4; ++r) {
                int row = m0 + wm + ms * 16 + fq * 4 + r;
                int col = n0 + wv + vs * 16 + fr;
                C[(size_t)row * Nsz + col] = acc[ms][vs][r];
            }
        }
    }
}

// ---------------- K2b: 128x64-tile f16-split GEMM (N=1024 path) ----------------
__global__ __launch_bounds__(256, 2) void k_gemm_n64(
        const _Float16* __restrict__ Ah, const _Float16* __restrict__ Al,
        const _Float16* __restrict__ Bh, const _Float16* __restrict__ Bl,
        float* __restrict__ C, int Nsz) {
    __shared__ __align__(16) unsigned char lds[24576];
    const int lane = threadIdx.x & 63;
    const int wid  = threadIdx.x >> 6;
    const int wm = (wid >> 1) * 64;
    const int wv = (wid & 1) * 32;
    const int n0 = blockIdx.x * 64;
    const int m0 = blockIdx.y * 128;
    const int fr = lane & 15, fq = lane >> 4;

    f32x4 acc[4][2] = {};

    for (int k0 = 0; k0 < 1024; k0 += 32) {
        #pragma unroll
        for (int j = 0; j < 6; ++j) {
            int cid = j * 4 + wid;
            const _Float16* bp;
            int rbase, ldsoff;
            if (cid < 16) {           // A: plane cid>>3, 16-row subtile cid&7
                bp = (cid >> 3) ? Al : Ah;
                rbase = m0 + (cid & 7) * 16 + fr;
                ldsoff = cid * 1024;
            } else {                  // B: plane (cid-16)>>2, subtile (cid-16)&3
                int r = cid - 16;
                bp = (r >> 2) ? Bl : Bh;
                rbase = n0 + (r & 3) * 16 + fr;
                ldsoff = 16384 + r * 1024;
            }
            async16(lds + ldsoff, bp + (size_t)rbase * 1024 + k0 + fq * 8);
        }
        __syncthreads();

        f16x8 ah[4], al[4];
        #pragma unroll
        for (int ms = 0; ms < 4; ++ms) {
            int off = ((wm >> 4) + ms) * 1024 + lane * 16;
            ah[ms] = *(const f16x8*)(lds + off);
            al[ms] = *(const f16x8*)(lds + 8192 + off);
        }
        #pragma unroll
        for (int vs = 0; vs < 2; ++vs) {
            int boff = ((wv >> 4) + vs) * 1024 + lane * 16;
            f16x8 bh = *(const f16x8*)(lds + 16384 + boff);
            f16x8 bl = *(const f16x8*)(lds + 20480 + boff);
            #pragma unroll
            for (int ms = 0; ms < 4; ++ms) {
                acc[ms][vs] = __builtin_amdgcn_mfma_f32_16x16x32_f16(ah[ms], bh, acc[ms][vs], 0, 0, 0);
                acc[ms][vs] = __builtin_amdgcn_mfma_f32_16x16x32_f16(ah[ms], bl, acc[ms][vs], 0, 0, 0);
                acc[ms][vs] = __builtin_amdgcn_mfma_f32_16x16x32_f16(al[ms], bh, acc[ms][vs], 0, 0, 0);
            }
        }
        __syncthreads();
    }

    #pragma unroll
    for (int ms = 0; ms < 4; ++ms) {
        #pragma unroll
        for (int vs = 0; vs < 2; ++vs) {
            #pragma unroll
            for (int r = 0; r < 4; ++r) {
                int row = m0 + wm + ms * 16 + fq * 4 + r;
                int col = n0 + wv + vs * 16 + fr;
                C[(size_t)row * Nsz + col] = acc[ms][vs][r];
            }
        }
    }
}

// ---------------- K3: fused conv + csilu + dt + z-gate + transpose ----------------
// 64(m) x 64(d) tile with 3-row halo staged in LDS: each XZ x1-element read
// once (was 4x, one per conv tap); DT m-major plane eliminated (only the old
// k_xpose consumed it); XrT/XiT/DTt written via LDS transpose (xpose pattern).
// Per-element fmaf order identical to old k_conv (halo taps become
// fmaf(0,k,acc) = bit-identical on finite inputs).
__global__ __launch_bounds__(256) void k_convx(const float* __restrict__ XZ,
        const float* __restrict__ ck, const float* __restrict__ dts,
        const float* __restrict__ dtb,
        float* __restrict__ Xr, float* __restrict__ Xi,
        float* __restrict__ ZUr, float* __restrict__ ZUi,
        float* __restrict__ DTt, float* __restrict__ XrT, float* __restrict__ XiT) {
    __shared__ float lr[67][65];
    __shared__ float li[67][65];
    int d0 = blockIdx.x * 64, m0 = blockIdx.y * 64;
    int b = m0 >> 10, s0 = m0 & (SS - 1);
    int tx = threadIdx.x & 63, ty = threadIdx.x >> 6;
    // phase 1: load x1 tile rows s0-3 .. s0+63 (zero outside batch)
    for (int t = ty; t < 67; t += 4) {
        int s = s0 + t - 3;
        float vr = 0.f, vi = 0.f;
        if (s >= 0) {
            size_t mm = ((size_t)(b << 10) + s) * 2048 + d0 + tx;
            vr = XZ[mm];
            vi = XZ[(size_t)MM * 2048 + mm];
        }
        lr[t][tx] = vr;
        li[t][tx] = vi;
    }
    __syncthreads();
    float4 kw = *(const float4*)(ck + (size_t)(d0 + tx) * KCC);
    float kwv[4] = {kw.x, kw.y, kw.z, kw.w};
    float dtsv = dts[d0 + tx], dtbv = dtb[d0 + tx];
    float xr16[16], xi16[16], dt16[16];
    #pragma unroll
    for (int k = 0; k < 16; ++k) {
        int r = ty + (k << 2);           // tile row 0..63; taps at lr[r..r+3]
        float cr = 0.f, ci = 0.f;
        #pragma unroll
        for (int j = 0; j < KCC; ++j) {
            cr = fmaf(lr[r + j][tx], kwv[j], cr);
            ci = fmaf(li[r + j][tx], kwv[j], ci);
        }
        float mag = sqrtf(cr * cr + ci * ci);
        float sg = 1.f / (1.f + expf(-mag));
        float xr = cr * sg, xi = ci * sg;
        xr16[k] = xr; xi16[k] = xi;
        dt16[k] = softplus_f(fmaf(xr, dtsv, dtbv));
        size_t i = (size_t)(m0 + r) * DD + d0 + tx;
        Xr[i] = xr; Xi[i] = xi;
        float zr = XZ[(size_t)(m0 + r) * 2048 + DD + d0 + tx];
        float zi = XZ[(size_t)(MM + m0 + r) * 2048 + DD + d0 + tx];
        float mz = sqrtf(zr * zr + zi * zi);
        float sz = 1.f / (1.f + expf(-mz));
        ZUr[i] = zr * sz; ZUi[i] = zi * sz;
    }
    __syncthreads();
    // phase 3: transpose xr/xi through LDS -> [bd][s]
    #pragma unroll
    for (int k = 0; k < 16; ++k) {
        int r = ty + (k << 2);
        lr[r][tx] = xr16[k];
        li[r][tx] = xi16[k];
    }
    __syncthreads();
    size_t tb = ((size_t)(b * DD + d0)) * SS + s0;
    #pragma unroll
    for (int k = 0; k < 16; ++k) {
        int dd = ty + (k << 2);
        XrT[tb + (size_t)dd * SS + tx] = lr[tx][dd];
        XiT[tb + (size_t)dd * SS + tx] = li[tx][dd];
    }
    __syncthreads();
    #pragma unroll
    for (int k = 0; k < 16; ++k) {
        int r = ty + (k << 2);
        lr[r][tx] = dt16[k];
    }
    __syncthreads();
    #pragma unroll
    for (int k = 0; k < 16; ++k) {
        int dd = ty + (k << 2);
        DTt[tb + (size_t)dd * SS + tx] = lr[tx][dd];
    }
}

// ---------------- K4: Bc/Cc projections -> packed BC2[(m*64+n)*4 + {br,bi,cr,ci}] ----------------
__global__ __launch_bounds__(256) void k_bc(const float* __restrict__ X,
        const float* __restrict__ WBp, const float* __restrict__ WCp,
        float* __restrict__ BC2) {
    __shared__ float xs[4][DD];
    __shared__ float red[4 * 256];
    int r0 = blockIdx.x * 4;
    for (int f = threadIdx.x; f < 4 * (DD / 4); f += 256) {
        int r = f / (DD / 4), c = (f % (DD / 4)) * 4;
        *(float4*)(&xs[r][c]) = *(const float4*)(X + (size_t)(r0 + r) * DD + c);
    }
    __syncthreads();
    int out = threadIdx.x & 127;
    int half = threadIdx.x >> 7;
    const float* Wrow = (out < 64) ? (WBp + (size_t)out * DD) : (WCp + (size_t)(out - 64) * DD);
    float acc[4] = {0.f, 0.f, 0.f, 0.f};
    for (int k = half * 512; k < half * 512 + 512; k += 4) {
        float4 w = *(const float4*)(Wrow + k);
        #pragma unroll
        for (int r = 0; r < 4; ++r) {
            float4 x4 = *(float4*)(&xs[r][k]);
            acc[r] = fmaf(x4.x, w.x, fmaf(x4.y, w.y, fmaf(x4.z, w.z, fmaf(x4.w, w.w, acc[r]))));
        }
    }
    #pragma unroll
    for (int r = 0; r < 4; ++r) red[r * 256 + threadIdx.x] = acc[r];
    __syncthreads();
    if (threadIdx.x < 128) {
        int isIm = (r0 >= MM) ? 1 : 0;
        int n = out & 63;
        int comp = ((out >> 6) << 1) | isIm;   // br=0, bi=1, cr=2, ci=3
        #pragma unroll
        for (int r = 0; r < 4; ++r) {
            float v = red[r * 256 + threadIdx.x] + red[r * 256 + threadIdx.x + 128];
            int m = (r0 + r) & (MM - 1);
            BC2[((size_t)m * 64 + n) * 4 + comp] = v;
        }
    }
}

// ---------------- K5a: scan pass 1, 4-step unrolled, vectorized T-plane loads ----------------
// Y8T: 8 planes [g16*2 + {r,i}][bd][s]. DTt/XrT/XiT in [bd][s]: one float4
// load per array per 4 steps (wave-uniform, contiguous).
__global__ __launch_bounds__(256, 8) void k_scan1(const float* __restrict__ XrT,
        const float* __restrict__ XiT, const float* __restrict__ DTt,
        const float4* __restrict__ BC2,
        const float* __restrict__ Alog, float* __restrict__ Y8T,
        float2* __restrict__ HB, float* __restrict__ SDT) {
    int w = (blockIdx.x << 2) + (threadIdx.x >> 6);   // (bd, c)
    int lane = threadIdx.x & 63;
    int c = w & (CH - 1);
    int bd = w / CH;
    int b = bd >> 10, d = bd & (DD - 1);
    float Av = -__expf(Alog[(size_t)d * NN + lane]);
    float hr = 0.f, hi = 0.f, sdt = 0.f;
    int s0 = c * LC;
    size_t mBase = (size_t)(b << 10);
    const float4* bcp = BC2 + (mBase + s0) * 64 + lane;
    size_t ys = (size_t)bd * SS + s0;
    size_t po = (size_t)(lane >> 4) * 2 * PS;
    for (int t = 0; t < LC; t += 4) {
        float4 dt4 = *(const float4*)(DTt + ys);
        float4 xr4 = *(const float4*)(XrT + ys);
        float4 xi4 = *(const float4*)(XiT + ys);
        float dtv[4] = {dt4.x, dt4.y, dt4.z, dt4.w};
        float xrv[4] = {xr4.x, xr4.y, xr4.z, xr4.w};
        float xiv[4] = {xi4.x, xi4.y, xi4.z, xi4.w};
        float4 yrq, yiq;
        #pragma unroll
        for (int k = 0; k < 4; ++k) {
            float4 bc = bcp[(size_t)k * 64];
            float g = __expf(dtv[k] * Av);
            float dxr = dtv[k] * xrv[k], dxi = dtv[k] * xiv[k];
            hr = fmaf(g, hr, fmaf(dxr, bc.x, -dxi * bc.y));
            hi = fmaf(g, hi, fmaf(dxr, bc.y,  dxi * bc.x));
            sdt += dtv[k];
            float pr = rsum16_dpp(hr * bc.z - hi * bc.w);
            float pi = rsum16_dpp(hr * bc.w + hi * bc.z);
            if (k == 0)      { yrq.x = pr; yiq.x = pi; }
            else if (k == 1) { yrq.y = pr; yiq.y = pi; }
            else if (k == 2) { yrq.z = pr; yiq.z = pi; }
            else             { yrq.w = pr; yiq.w = pi; }
        }
        bcp += 256;
        if ((lane & 15) == 15) {
            *(float4*)(Y8T + po + ys)      = yrq;
            *(float4*)(Y8T + po + PS + ys) = yiq;
        }
        ys += 4;
    }
    HB[((size_t)c * BDW + bd) * NN + lane] = make_float2(hr, hi);
    if (lane == 0) SDT[c * BDW + bd] = sdt;
}

// ---------------- K5c: inflow correction, 4-step unrolled, vectorized DT load ----------------
__global__ __launch_bounds__(256, 8) void k_scan3(const float* __restrict__ DTt,
        const float* __restrict__ BC2, const float* __restrict__ Alog,
        const float2* __restrict__ HB, const float* __restrict__ SDT,
        float* __restrict__ Y8T) {
    int w = (blockIdx.x << 2) + (threadIdx.x >> 6);   // [0, (CH-1)*BDW)
    int lane = threadIdx.x & 63;
    int cm1 = w / BDW;           // 0..CH-2 -> chunk c = cm1+1
    int bd = w % BDW;
    int b = bd >> 10, d = bd & (DD - 1);
    float Av = -__expf(Alog[(size_t)d * NN + lane]);
    float2 h0 = HB[(size_t)bd * NN + lane];
    float hr = h0.x, hi = h0.y;
    if (cm1 >= 1) {
        float2 h1 = HB[((size_t)1 * BDW + bd) * NN + lane];
        float P1 = __expf(Av * SDT[1 * BDW + bd]);
        hr = fmaf(P1, hr, h1.x); hi = fmaf(P1, hi, h1.y);
        if (cm1 >= 2) {
            float2 h2 = HB[((size_t)2 * BDW + bd) * NN + lane];
            float P2 = __expf(Av * SDT[2 * BDW + bd]);
            hr = fmaf(P2, hr, h2.x); hi = fmaf(P2, hi, h2.y);
        }
    }
    int s0 = (cm1 + 1) * LC;
    size_t mBase = (size_t)(b << 10);
    const float* ccp = BC2 + ((mBase + s0) * 64 + lane) * 4 + 2;
    size_t ys = (size_t)bd * SS + s0;
    size_t po = (size_t)(lane >> 4) * 2 * PS;
    for (int t = 0; t < LC; t += 4) {
        float4 dt4 = *(const float4*)(DTt + ys);
        float dtv[4] = {dt4.x, dt4.y, dt4.z, dt4.w};
        float4 yrq, yiq;
        #pragma unroll
        for (int k = 0; k < 4; ++k) {
            float2 cc = *(const float2*)(ccp + (size_t)k * 256);
            float g = __expf(dtv[k] * Av);
            hr *= g; hi *= g;
            float pr = rsum16_dpp(hr * cc.x - hi * cc.y);
            float pi = rsum16_dpp(hr * cc.y + hi * cc.x);
            if (k == 0)      { yrq.x = pr; yiq.x = pi; }
            else if (k == 1) { yrq.y = pr; yiq.y = pi; }
            else if (k == 2) { yrq.z = pr; yiq.z = pi; }
            else             { yrq.w = pr; yiq.w = pi; }
        }
        ccp += 1024;
        if ((lane & 15) == 15) {
            float4 orq = *(float4*)(Y8T + po + ys);
            float4 oiq = *(float4*)(Y8T + po + PS + ys);
            orq.x += yrq.x; orq.y += yrq.y; orq.z += yrq.z; orq.w += yrq.w;
            oiq.x += yiq.x; oiq.y += yiq.y; oiq.z += yiq.z; oiq.w += yiq.w;
            *(float4*)(Y8T + po + ys)      = orq;
            *(float4*)(Y8T + po + PS + ys) = oiq;
        }
        ys += 4;
    }
}

// ---------------- K6: y = (sum Y8T partials + Dk*x1) * csilu(z) -> f16 hi/lo ----------------
__global__ __launch_bounds__(256) void k_ymod(const float* __restrict__ Y8T,
        const float* __restrict__ X, const float* __restrict__ ZUr,
        const float* __restrict__ ZUi, const float* __restrict__ Dk,
        _Float16* __restrict__ YOh, _Float16* __restrict__ YOl) {
    __shared__ float tr[64][65];
    __shared__ float ti[64][65];
    int d0 = blockIdx.x * 64, m0 = blockIdx.y * 64;
    int b = m0 >> 10, s0 = m0 & (SS - 1);
    int t = threadIdx.x;
    int rr = t >> 2, c0 = (t & 3) * 4;
    size_t ybase = (size_t)(b * DD + d0 + rr) * SS + s0;
    #pragma unroll
    for (int j = 0; j < 4; ++j) {
        size_t o = ybase + c0 + j * 16;
        float4 r0 = *(const float4*)(Y8T + o);
        float4 r1 = *(const float4*)(Y8T + 2 * PS + o);
        float4 r2 = *(const float4*)(Y8T + 4 * PS + o);
        float4 r3 = *(const float4*)(Y8T + 6 * PS + o);
        float4 i0 = *(const float4*)(Y8T + PS + o);
        float4 i1 = *(const float4*)(Y8T + 3 * PS + o);
        float4 i2 = *(const float4*)(Y8T + 5 * PS + o);
        float4 i3 = *(const float4*)(Y8T + 7 * PS + o);
        float4 vr, vi;
        vr.x = (r3.x + r2.x) + (r1.x + r0.x);
        vr.y = (r3.y + r2.y) + (r1.y + r0.y);
        vr.z = (r3.z + r2.z) + (r1.z + r0.z);
        vr.w = (r3.w + r2.w) + (r1.w + r0.w);
        vi.x = (i3.x + i2.x) + (i1.x + i0.x);
        vi.y = (i3.y + i2.y) + (i1.y + i0.y);
        vi.z = (i3.z + i2.z) + (i1.z + i0.z);
        vi.w = (i3.w + i2.w) + (i1.w + i0.w);
        int sl = c0 + j * 16;
        tr[sl + 0][rr] = vr.x; tr[sl + 1][rr] = vr.y; tr[sl + 2][rr] = vr.z; tr[sl + 3][rr] = vr.w;
        ti[sl + 0][rr] = vi.x; ti[sl + 1][rr] = vi.y; ti[sl + 2][rr] = vi.z; ti[sl + 3][rr] = vi.w;
    }
    __syncthreads();
    int td = t & 63, tq = t >> 6;
    float dk = Dk[d0 + td];
    #pragma unroll
    for (int k = 0; k < 16; ++k) {
        int tm = tq * 16 + k;
        size_t i = (size_t)(m0 + tm) * DD + d0 + td;
        float yr = tr[tm][td];
        float yi = ti[tm][td];
        yr = fmaf(dk, X[i], yr);
        yi = fmaf(dk, X[PS + i], yi);
        float zr = ZUr[i], zi = ZUi[i];
        float or_ = yr * zr - yi * zi;
        float oi_ = yr * zi + yi * zr;
        _Float16 h0 = (_Float16)or_, h1 = (_Float16)oi_;
        YOh[i] = h0;      YOl[i] = (_Float16)(or_ - (float)h0);
        YOh[PS + i] = h1; YOl[PS + i] = (_Float16)(oi_ - (float)h1);
    }
}

// ---------------- K8: fused proj + correct (wave per row) ----------------
__global__ __launch_bounds__(256) void k_projcorr(float* __restrict__ BR,
        const float* __restrict__ Lop) {
    int row = (blockIdx.x << 2) + (threadIdx.x >> 6);
    int lane = threadIdx.x & 63;
    float* br = BR + (size_t)row * DD;
    float4 v[4], lw[4][4];
    float acc[4] = {0.f, 0.f, 0.f, 0.f};
    #pragma unroll
    for (int j = 0; j < 4; ++j) {
        int col = lane * 4 + j * 256;
        v[j] = *(const float4*)(br + col);
        #pragma unroll
        for (int k = 0; k < 4; ++k) {
            lw[j][k] = *(const float4*)(Lop + (size_t)k * DD + col);
            acc[k] += v[j].x * lw[j][k].x + v[j].y * lw[j][k].y
                    + v[j].z * lw[j][k].z + v[j].w * lw[j][k].w;
        }
    }
    #pragma unroll
    for (int off = 1; off <= 32; off <<= 1) {
        #pragma unroll
        for (int k = 0; k < 4; ++k) acc[k] += __shfl_xor(acc[k], off, 64);
    }
    #pragma unroll
    for (int j = 0; j < 4; ++j) {
        int col = lane * 4 + j * 256;
        float4 o;
        o.x = v[j].x - GAMMA_F * (acc[0]*lw[j][0].x + acc[1]*lw[j][1].x + acc[2]*lw[j][2].x + acc[3]*lw[j][3].x);
        o.y = v[j].y - GAMMA_F * (acc[0]*lw[j][0].y + acc[1]*lw[j][1].y + acc[2]*lw[j][2].y + acc[3]*lw[j][3].y);
        o.z = v[j].z - GAMMA_F * (acc[0]*lw[j][0].z + acc[1]*lw[j][1].z + acc[2]*lw[j][2].z + acc[3]*lw[j][3].z);
        o.w = v[j].w - GAMMA_F * (acc[0]*lw[j][0].w + acc[1]*lw[j][1].w + acc[2]*lw[j][2].w + acc[3]*lw[j][3].w);
        *(float4*)(br + col) = o;
    }
}

// ---------------- K9b: diag ----------------
__global__ __launch_bounds__(256) void k_diag(const float* __restrict__ BR,
        float* __restrict__ DG_) {
    __shared__ float red[4][64];
    int b = blockIdx.y, d0 = blockIdx.x * 64;
    int sg = threadIdx.x >> 6, ld = threadIdx.x & 63;
    float acc = 0.f;
    for (int s = sg; s < SS; s += 4) {
        size_t m = (size_t)(b * SS + s) * DD + d0 + ld;
        float r = BR[m], ii = BR[PS + m];
        acc = fmaf(r, r, fmaf(ii, ii, acc));
    }
    red[sg][ld] = acc;
    __syncthreads();
    if (threadIdx.x < 64) {
        float v = red[0][threadIdx.x] + red[1][threadIdx.x] + red[2][threadIdx.x] + red[3][threadIdx.x];
        DG_[b * DD + d0 + threadIdx.x] = v * (1.f / SS);
    }
}

// ---------------- K10: phase ----------------
__global__ __launch_bounds__(256) void k_phase(const float* __restrict__ DG_,
        float* __restrict__ PH) {
    __shared__ float mx[256], mn[256];
    int b = blockIdx.x;
    float vmax = -1e30f, vmin = 1e30f;
    for (int d = threadIdx.x; d < DD; d += 256) {
        float v = DG_[b * DD + d];
        vmax = fmaxf(vmax, v); vmin = fminf(vmin, v);
    }
    mx[threadIdx.x] = vmax; mn[threadIdx.x] = vmin;
    __syncthreads();
    for (int st = 128; st >= 1; st >>= 1) {
        if (threadIdx.x < st) {
            mx[threadIdx.x] = fmaxf(mx[threadIdx.x], mx[threadIdx.x + st]);
            mn[threadIdx.x] = fminf(mn[threadIdx.x], mn[threadIdx.x + st]);
        }
        __syncthreads();
    }
    if (threadIdx.x == 0) {
        float cond = mx[0] / (mn[0] + 1e-8f);
        bool ap = cond > 100.0f;
        PH[b * 2 + 0] = ap ? PHASE_COS : 1.f;
        PH[b * 2 + 1] = ap ? PHASE_SIN : 0.f;
    }
}

// ---------------- K11: residual + psi f16 split (x4 vec) ----------------
__global__ __launch_bounds__(256) void k_resid(float* __restrict__ Pr,
        float* __restrict__ Pi, const float* __restrict__ BR,
        const float* __restrict__ PH,
        _Float16* __restrict__ Ph, _Float16* __restrict__ Pl) {
    size_t i = ((size_t)blockIdx.x * 256 + threadIdx.x) * 4;
    int b = (int)(i >> 20);
    float pr = PH[b * 2], pih = PH[b * 2 + 1];
    float4 brr4 = *(const float4*)(BR + i);
    float4 bri4 = *(const float4*)(BR + PS + i);
    float4 pr4  = *(const float4*)(Pr + i);
    float4 pi4  = *(const float4*)(Pi + i);
    float brr[4] = {brr4.x, brr4.y, brr4.z, brr4.w};
    float bri[4] = {bri4.x, bri4.y, bri4.z, bri4.w};
    float pro[4] = {pr4.x, pr4.y, pr4.z, pr4.w};
    float pio[4] = {pi4.x, pi4.y, pi4.z, pi4.w};
    f16x4 rh, rl, ih, il;
    float nr[4], ni[4];
    #pragma unroll
    for (int c = 0; c < 4; ++c) {
        nr[c] = fmaf(SCALE_F, brr[c] * pr - bri[c] * pih, pro[c]);
        ni[c] = fmaf(SCALE_F, brr[c] * pih + bri[c] * pr, pio[c]);
        _Float16 h0 = (_Float16)nr[c]; rh[c] = h0; rl[c] = (_Float16)(nr[c] - (float)h0);
        _Float16 h1 = (_Float16)ni[c]; ih[c] = h1; il[c] = (_Float16)(ni[c] - (float)h1);
    }
    *(float4*)(Pr + i) = make_float4(nr[0], nr[1], nr[2], nr[3]);
    *(float4*)(Pi + i) = make_float4(ni[0], ni[1], ni[2], ni[3]);
    *(f16x4*)(Ph + i) = rh;      *(f16x4*)(Pl + i) = rl;
    *(f16x4*)(Ph + PS + i) = ih; *(f16x4*)(Pl + PS + i) = il;
}

// ---------------- K12: RMS norm -> f16 hi/lo split planes ----------------
__global__ __launch_bounds__(256) void k_rms(const float* __restrict__ Pr,
        const float* __restrict__ Pi, const float* __restrict__ nw,
        _Float16* __restrict__ Sp) {   // Sp: Rh | Rl | Ih | Il
    __shared__ float red[256];
    int m = blockIdx.x;
    int d = threadIdx.x * 4;
    float4 r  = *(const float4*)(Pr + (size_t)m * DD + d);
    float4 ii = *(const float4*)(Pi + (size_t)m * DD + d);
    float acc = r.x*r.x + r.y*r.y + r.z*r.z + r.w*r.w
              + ii.x*ii.x + ii.y*ii.y + ii.z*ii.z + ii.w*ii.w;
    red[threadIdx.x] = acc;
    __syncthreads();
    for (int st = 128; st >= 1; st >>= 1) {
        if (threadIdx.x < st) red[threadIdx.x] += red[threadIdx.x + st];
        __syncthreads();
    }
    float inv = 1.f / sqrtf(red[0] * (1.f / DD) + 1e-8f);
    float4 w = *(const float4*)(nw + d);
    float qr[4] = {r.x*inv*w.x, r.y*inv*w.y, r.z*inv*w.z, r.w*inv*w.w};
    float qi[4] = {ii.x*inv*w.x, ii.y*inv*w.y, ii.z*inv*w.z, ii.w*inv*w.w};
    f16x4 rh, rl, ih, il;
    #pragma unroll
    for (int j = 0; j < 4; ++j) {
        _Float16 h = (_Float16)qr[j]; rh[j] = h; rl[j] = (_Float16)(qr[j] - (float)h);
        _Float16 g = (_Float16)qi[j]; ih[j] = g; il[j] = (_Float16)(qi[j] - (float)g);
    }
    size_t o = (size_t)m * DD + d;
    *(f16x4*)(Sp + o)          = rh;
    *(f16x4*)(Sp + PS + o)     = rl;
    *(f16x4*)(Sp + 2 * PS + o) = ih;
    *(f16x4*)(Sp + 3 * PS + o) = il;
}

// ---------------- K12b: split emb_r f32 -> f16 hi/lo ----------------
__global__ __launch_bounds__(256) void k_split_e(const float* __restrict__ E,
        _Float16* __restrict__ Eh, _Float16* __restrict__ El) {
    size_t i = (size_t)(blockIdx.x * 256 + threadIdx.x) * 8;
    float4 a = *(const float4*)(E + i);
    float4 b = *(const float4*)(E + i + 4);
    float v[8] = {a.x, a.y, a.z, a.w, b.x, b.y, b.z, b.w};
    f16x8 hi, lo;
    #pragma unroll
    for (int j = 0; j < 8; ++j) {
        _Float16 h = (_Float16)v[j];
        hi[j] = h; lo[j] = (_Float16)(v[j] - (float)h);
    }
    *(f16x8*)(Eh + i) = hi;
    *(f16x8*)(El + i) = lo;
}

// ---------------- K13: MFMA f16-split logits GEMM (round-9 form, best known) ----------------
// XCD-pinned mapping: XCD x owns m-tiles {2x, 2x+1} (A = 2MB, L2-resident);
// all XCDs sweep v in lockstep so each E-tile is L3-fetched once, read 16x.
__global__ __launch_bounds__(256, 2) void k_logits_mfma(
        const _Float16* __restrict__ Sp,   // Rh|Rl|Ih|Il planes
        const _Float16* __restrict__ Eh, const _Float16* __restrict__ El,
        float* __restrict__ out) {
    __shared__ __align__(16) unsigned char lds[49152];
    const int lane = threadIdx.x & 63;
    const int wid  = threadIdx.x >> 6;
    const int wm = (wid >> 1) * 64;
    const int wv = (wid & 1) * 64;
    const int fr = lane & 15, fq = lane >> 4;
    int x = blockIdx.x & 7;
    int j = blockIdx.x >> 3;
    const int m0 = ((x << 1) | (j & 1)) << 7;
    const int v0 = (j >> 1) << 7;

    f32x4 accR[4][4] = {};
    f32x4 accI[4][4] = {};

    for (int k0 = 0; k0 < DD; k0 += 32) {
        #pragma unroll
        for (int jj = 0; jj < 12; ++jj) {
            int cid = jj * 4 + wid;
            const _Float16* src;
            int ldsoff;
            if (cid < 32) {            // A: plane p, 16-row subtile c
                int p = cid >> 3, c = cid & 7;
                src = Sp + (size_t)p * PS + (size_t)(m0 + c * 16 + fr) * DD + k0 + fq * 8;
                ldsoff = p * 8192 + c * 1024;
            } else {                   // B: Eh/El
                int r = cid - 32;
                int q = r >> 3, c = r & 7;
                const _Float16* Ep = q ? El : Eh;
                src = Ep + (size_t)(v0 + c * 16 + fr) * DD + k0 + fq * 8;
                ldsoff = 32768 + q * 8192 + c * 1024;
            }
            async16(lds + ldsoff, src);
        }
        __syncthreads();

        f16x8 aRh[4], aRl[4], aIh[4], aIl[4];
        #pragma unroll
        for (int ms = 0; ms < 4; ++ms) {
            int off = ((wm >> 4) + ms) * 1024 + lane * 16;
            aRh[ms] = *(const f16x8*)(lds + off);
            aRl[ms] = *(const f16x8*)(lds + 8192 + off);
            aIh[ms] = *(const f16x8*)(lds + 16384 + off);
            aIl[ms] = *(const f16x8*)(lds + 24576 + off);
        }
        #pragma unroll
        for (int vs = 0; vs < 4; ++vs) {
            int boff = ((wv >> 4) + vs) * 1024 + lane * 16;
            f16x8 bh = *(const f16x8*)(lds + 32768 + boff);
            f16x8 bl = *(const f16x8*)(lds + 40960 + boff);
            #pragma unroll
            for (int ms = 0; ms < 4; ++ms) {
                accR[ms][vs] = __builtin_amdgcn_mfma_f32_16x16x32_f16(aRh[ms], bh, accR[ms][vs], 0, 0, 0);
                accR[ms][vs] = __builtin_amdgcn_mfma_f32_16x16x32_f16(aRh[ms], bl, accR[ms][vs], 0, 0, 0);
                accR[ms][vs] = __builtin_amdgcn_mfma_f32_16x16x32_f16(aRl[ms], bh, accR[ms][vs], 0, 0, 0);
                accI[ms][vs] = __builtin_amdgcn_mfma_f32_16x16x32_f16(aIh[ms], bh, accI[ms][vs], 0, 0, 0);
                accI[ms][vs] = __builtin_amdgcn_mfma_f32_16x16x32_f16(aIh[ms], bl, accI[ms][vs], 0, 0, 0);
                accI[ms][vs] = __builtin_amdgcn_mfma_f32_16x16x32_f16(aIl[ms], bh, accI[ms][vs], 0, 0, 0);
            }
        }
        __syncthreads();
    }

    #pragma unroll
    for (int ms = 0; ms < 4; ++ms) {
        #pragma unroll
        for (int vs = 0; vs < 4; ++vs) {
            #pragma unroll
            for (int r = 0; r < 4; ++r) {
                int row = m0 + wm + ms * 16 + fq * 4 + r;
                int col = v0 + wv + vs * 16 + fr;
                float ar = accR[ms][vs][r], ai = accI[ms][vs][r];
                out[(size_t)row * VV + col] = logf(fmaf(ar, ar, fmaf(ai, ai, 1e-8f)));
            }
        }
    }
}

extern "C" void kernel_launch(void* const* d_in, const int* in_sizes, int n_in,
                              void* d_out, int out_size, void* d_ws, size_t ws_size,
                              hipStream_t stream) {
    const int*   tok  = (const int*)d_in[0];
    const float* er   = (const float*)d_in[1];
    const float* ei   = (const float*)d_in[2];
    const float* Win  = (const float*)d_in[3];
    const float* ck   = (const float*)d_in[4];
    const float* Alog = (const float*)d_in[5];
    const float* dts  = (const float*)d_in[6];
    const float* dtb  = (const float*)d_in[7];
    const float* WB   = (const float*)d_in[8];
    const float* WC   = (const float*)d_in[9];
    const float* Dk   = (const float*)d_in[10];
    const float* Wo   = (const float*)d_in[11];
    const float* Lop  = (const float*)d_in[12];
    const float* nw   = (const float*)d_in[13];
    float* out = (float*)d_out;

    float* W0   = (float*)d_ws;
    float* P    = W0;                 // planes 0,1: psi f32
    float* XZ   = W0 + 2 * PS;        // planes 2..5 (layer phase)
    float* X    = W0 + 6 * PS;        // planes 6,7
    float* ZU   = W0 + 9 * PS;        // planes 9,10
    float* Y8T  = W0 + 11 * PS;       // planes 11..18 (8 partial planes, [g][bd][s])
    _Float16* YOh = (_Float16*)(W0 + 19 * PS);
    _Float16* YOl = (_Float16*)(W0 + 20 * PS);
    _Float16* Ph  = (_Float16*)(W0 + 21 * PS);
    _Float16* Pl  = (_Float16*)(W0 + 22 * PS);
    float* BR   = XZ;                 // alias planes 2,3 (written by gemm2, after T-planes dead)
    // T-planes for scans: aliases (XZ planes 2,3 dead after convx; plane 8 free)
    float* DTt  = W0 + 8 * PS;
    float* XrT  = W0 + 2 * PS;
    float* XiT  = W0 + 3 * PS;
    // small arrays: planes 23,24
    float* BC2  = W0 + 23 * PS;                    // MM*64*4 floats (2MB)
    float* DIAG = BC2 + (size_t)MM * 64 * 4;
    float* PH   = DIAG + BB * DD;
    float2* HB  = (float2*)(PH + 16);              // CH*BDW*NN float2
    float* SDT  = (float*)(HB + (size_t)CH * BDW * NN);
    // weight splits (transposed): planes 25..30
    _Float16* Winh = (_Float16*)(W0 + 25 * PS);
    _Float16* Winl = (_Float16*)(W0 + 27 * PS);
    _Float16* Woh  = (_Float16*)(W0 + 29 * PS);
    _Float16* Wol  = (_Float16*)(W0 + 30 * PS);
    // end phase (layer buffers dead)
    _Float16* Sp  = (_Float16*)(W0 + 2 * PS);
    _Float16* Ehp = (_Float16*)(W0 + 4 * PS);
    _Float16* Elp = (_Float16*)(W0 + 13 * PS);

    k_split_w<<<dim3(32, 64, 4), 256, 0, stream>>>(Win, Winh, Winl, 1024, 2048);
    k_split_w<<<dim3(32, 32, 4), 256, 0, stream>>>(Wo, Woh, Wol, 1024, 1024);

    k_embed<<<(int)(PS / 4 / 256), 256, 0, stream>>>(tok, er, ei, P, P + PS, Ph, Pl);

    for (int l = 0; l < LLAYERS; ++l) {
        const float* Lopl = Lop + (size_t)l * KLL * DD;
        const float* Alogl = Alog + (size_t)l * DD * NN;
        const _Float16* Wih = Winh + (size_t)l * 2048 * 1024;
        const _Float16* Wil = Winl + (size_t)l * 2048 * 1024;
        const _Float16* Wohl = Woh + (size_t)l * 1024 * 1024;
        const _Float16* Woll = Wol + (size_t)l * 1024 * 1024;

        k_gemm_f16<<<dim3(2048 / 128, M2 / 128), 256, 0, stream>>>(Ph, Pl, Wih, Wil, XZ, 2048);
        // NOTE: convx writes XrT/XiT into planes 2,3 (first halves of XZ planes are
        // x1 values, consumed from LDS before overwrite? No -- convx READS XZ from
        // global while planes 2,3 hold XZ real rows. XrT aliases plane 2 = XZ real!
        // Writing XrT would corrupt XZ mid-kernel. Use planes dead at this point:
        // DTt=plane 8 (free), XrT/XiT must NOT alias XZ. Use planes 4,5 (XZ cols
        // 1024..2047 = z-part, consumed within the same convx thread BEFORE any
        // transposed write? Not guaranteed across blocks.) -> use scratch planes
        // 19,20 (YOh/YOl, dead until ymod) instead. See pointers below.
        k_convx<<<dim3(DD / 64, MM / 64), 256, 0, stream>>>(XZ, ck + (size_t)l * DD * KCC,
                dts + l * DD, dtb + l * DD, X, X + PS, ZU, ZU + PS,
                DTt, (float*)YOh, (float*)YOl);
        k_bc<<<M2 / 4, 256, 0, stream>>>(X, WB + (size_t)l * NN * DD, WC + (size_t)l * NN * DD, BC2);
        k_scan1<<<(BDW * CH) / 4, 256, 0, stream>>>((const float*)YOh, (const float*)YOl, DTt,
                (const float4*)BC2, Alogl, Y8T, HB, SDT);
        k_scan3<<<(BDW * (CH - 1)) / 4, 256, 0, stream>>>(DTt, BC2, Alogl, HB, SDT, Y8T);
        k_ymod<<<dim3(DD / 64, MM / 64), 256, 0, stream>>>(Y8T, X, ZU, ZU + PS, Dk + l * DD, YOh, YOl);
        k_gemm_n64<<<dim3(1024 / 64, M2 / 128), 256, 0, stream>>>(YOh, YOl, Wohl, Woll, BR, 1024);
        k_projcorr<<<M2 / 4, 256, 0, stream>>>(BR, Lopl);
        k_diag<<<dim3(DD / 64, BB), 256, 0, stream>>>(BR, DIAG);
        k_phase<<<BB, 256, 0, stream>>>(DIAG, PH);
        k_resid<<<(int)(PS / 4 / 256), 256, 0, stream>>>(P, P + PS, BR, PH, Ph, Pl);
    }

    k_rms<<<MM, 256, 0, stream>>>(P, P + PS, nw, Sp);
    k_split_e<<<(int)((size_t)VV * DD / 8 / 256), 256, 0, stream>>>(er, Ehp, Elp);
    k_logits_mfma<<<4000, 256, 0, stream>>>(Sp, Ehp, Elp, out);
}